// Round 7
// baseline (124.775 us; speedup 1.0000x reference)
//
#include <hip/hip_runtime.h>

#define LN_EPS 1e-5f

typedef __attribute__((ext_vector_type(8))) short s16x8;
typedef __attribute__((ext_vector_type(4))) float f32x4;

__device__ inline unsigned int pk_bf16(float a, float b) {
    unsigned ua = __builtin_bit_cast(unsigned, a);
    unsigned ub = __builtin_bit_cast(unsigned, b);
    ua += 0x7fffu + ((ua >> 16) & 1u);
    ub += 0x7fffu + ((ub >> 16) & 1u);
    return (ua >> 16) | (ub & 0xffff0000u);
}
__device__ inline float bf2f(unsigned short h) {
    unsigned u = ((unsigned)h) << 16;
    return __builtin_bit_cast(float, u);
}

__device__ inline void gl_lds16(const void* g, void* l) {
    __builtin_amdgcn_global_load_lds((const __attribute__((address_space(1))) void*)g,
                                     (__attribute__((address_space(3))) void*)l, 16, 0, 0);
}

// ---------------- K1: degree pass + masked bf16 adjacency ----------------
__global__ __launch_bounds__(256) void k_deg(const float* __restrict__ adj,
                                             const int* __restrict__ pm,
                                             const float* __restrict__ ew,
                                             float* __restrict__ dis_o,
                                             float* __restrict__ rs,
                                             float* __restrict__ rself,
                                             unsigned short* __restrict__ am,
                                             int L) {
    int row = blockIdx.x;
    int b = row / L;
    int i = row - b * L;
    const float* arow = adj + (size_t)row * L;
    const int* pmb = pm + (size_t)b * L;
    unsigned short* amrow = am + (size_t)row * L;
    int t = threadIdx.x;
    float validi = (pmb[i] == 0) ? 1.f : 0.f;
    float s = 0.f;
    for (int j0 = t * 8; j0 < L; j0 += 2048) {
        float4 a0 = *(const float4*)(arow + j0);
        float4 a1 = *(const float4*)(arow + j0 + 4);
        int4 p0 = *(const int4*)(pmb + j0);
        int4 p1 = *(const int4*)(pmb + j0 + 4);
        float m0 = p0.x == 0 ? a0.x : 0.f;
        float m1 = p0.y == 0 ? a0.y : 0.f;
        float m2 = p0.z == 0 ? a0.z : 0.f;
        float m3 = p0.w == 0 ? a0.w : 0.f;
        float m4 = p1.x == 0 ? a1.x : 0.f;
        float m5 = p1.y == 0 ? a1.y : 0.f;
        float m6 = p1.z == 0 ? a1.z : 0.f;
        float m7 = p1.w == 0 ? a1.w : 0.f;
        s += ((m0 + m1) + (m2 + m3)) + ((m4 + m5) + (m6 + m7));
        uint4 o;
        o.x = pk_bf16(validi * m0, validi * m1);
        o.y = pk_bf16(validi * m2, validi * m3);
        o.z = pk_bf16(validi * m4, validi * m5);
        o.w = pk_bf16(validi * m6, validi * m7);
        *(uint4*)(amrow + j0) = o;
    }
    #pragma unroll
    for (int off = 32; off; off >>= 1) s += __shfl_down(s, off);
    __shared__ float wsum[4];
    if ((t & 63) == 0) wsum[t >> 6] = s;
    __syncthreads();
    if (t == 0) {
        float tot = wsum[0] + wsum[1] + wsum[2] + wsum[3];
        float deg = 1.f + validi * tot;   // >= 1 (self-loop)
        float d = rsqrtf(deg);
        float e = ew[0];
        dis_o[row]  = d;
        rs[row]     = e * validi * d;
        rself[row]  = e * d * d;
    }
}

// ---------------- K2: x -> yht[b,d,l] (bf16, dis-scaled, transposed) + xb (bf16 row-major)
//                  + folded W->Wh convert in the extra gridDim.x slot ----------------
__global__ __launch_bounds__(256) void k_xt(const float* __restrict__ x,
                                            const float* __restrict__ dis,
                                            const float* __restrict__ W,
                                            unsigned short* __restrict__ yht,
                                            unsigned short* __restrict__ xb,
                                            unsigned short* __restrict__ Wh,
                                            int L, int D) {
    if (blockIdx.x == gridDim.x - 1) {     // W -> bf16 (64 blocks via y,z)
        int seg = blockIdx.z * gridDim.y + blockIdx.y;     // 0..63
        int i = (seg * 256 + threadIdx.x) * 16;            // 64*256*16 = 262144 = D*D
        #pragma unroll
        for (int k = 0; k < 16; k += 4) {
            float4 v = *(const float4*)(W + i + k);
            uint2 o;
            o.x = pk_bf16(v.x, v.y);
            o.y = pk_bf16(v.z, v.w);
            *(uint2*)(Wh + i + k) = o;
        }
        return;
    }
    __shared__ float tile[64][65];
    int l0 = blockIdx.x << 6, d0 = blockIdx.y << 6, b = blockIdx.z;
    int t = threadIdx.x;
    int lr = t >> 2, c4 = (t & 3) << 4;
    float dl = dis[(size_t)b * L + l0 + lr];
    const float* xp = x + ((size_t)b * L + l0 + lr) * D + d0 + c4;
    unsigned short* xbp = xb + ((size_t)b * L + l0 + lr) * D + d0 + c4;
    #pragma unroll
    for (int k = 0; k < 16; k += 4) {
        float4 v = *(const float4*)(xp + k);
        uint2 o;
        o.x = pk_bf16(v.x, v.y);
        o.y = pk_bf16(v.z, v.w);
        *(uint2*)(xbp + k) = o;            // unscaled x, bf16
        tile[lr][c4 + k + 0] = v.x * dl;
        tile[lr][c4 + k + 1] = v.y * dl;
        tile[lr][c4 + k + 2] = v.z * dl;
        tile[lr][c4 + k + 3] = v.w * dl;
    }
    __syncthreads();
    int dr = t >> 2, k0 = (t & 3) << 4;
    unsigned short* op = yht + ((size_t)b * D + d0 + dr) * L + l0 + k0;
    uint4 o0, o1;
    o0.x = pk_bf16(tile[k0 + 0][dr],  tile[k0 + 1][dr]);
    o0.y = pk_bf16(tile[k0 + 2][dr],  tile[k0 + 3][dr]);
    o0.z = pk_bf16(tile[k0 + 4][dr],  tile[k0 + 5][dr]);
    o0.w = pk_bf16(tile[k0 + 6][dr],  tile[k0 + 7][dr]);
    o1.x = pk_bf16(tile[k0 + 8][dr],  tile[k0 + 9][dr]);
    o1.y = pk_bf16(tile[k0 + 10][dr], tile[k0 + 11][dr]);
    o1.z = pk_bf16(tile[k0 + 12][dr], tile[k0 + 13][dr]);
    o1.w = pk_bf16(tile[k0 + 14][dr], tile[k0 + 15][dr]);
    *(uint4*)(op) = o0;
    *(uint4*)(op + 8) = o1;
}

// ---------------- K3: agg = rs_i * (am @ y) + rself_i * x ----------------
// MFMA bf16; BM=BN=128, BK=64; 4 waves of 64x64; dbuf + counted vmcnt.
__global__ __launch_bounds__(256, 2) void k_aggmm(
    const unsigned short* __restrict__ am,
    const unsigned short* __restrict__ yht,
    const unsigned short* __restrict__ xb,
    const float* __restrict__ rs,
    const float* __restrict__ rself,
    unsigned short* __restrict__ aggh,
    int L, int D)
{
    __shared__ __align__(16) unsigned short As[2][128 * 64];
    __shared__ __align__(16) unsigned short Bs[2][128 * 64];
    int bid = blockIdx.x;
    int wid = (bid & 7) * 64 + (bid >> 3);   // one batch per XCD (512 = 8*64, bijective)
    int b   = wid >> 6;
    int t6  = wid & 63;
    int brow = (t6 >> 2) << 7;
    int bcol = (t6 & 3) << 7;

    int t = threadIdx.x;
    int lane = t & 63;
    int w = t >> 6;
    int wr = ((w >> 1) & 1) << 6;
    int wc = (w & 1) << 6;

    const unsigned short* amb = am + ((size_t)b * L + brow) * L;
    const unsigned short* yb  = yht + ((size_t)b * D + bcol) * L;

    int srow = t >> 3;          // 0..31 (= w*8 + lane>>3: lane-linear dest)
    int chunk = t & 7;

    f32x4 acc[4][4];
    #pragma unroll
    for (int i = 0; i < 4; ++i)
        #pragma unroll
        for (int j = 0; j < 4; ++j)
            acc[i][j] = (f32x4){0.f, 0.f, 0.f, 0.f};

    const int lane15 = lane & 15;
    const int kbyte = (lane >> 4) << 4;
    const int swa = (lane & 7) << 4;

    {
        char* Ad = (char*)As[0];
        char* Bd = (char*)Bs[0];
        #pragma unroll
        for (int q = 0; q < 4; ++q) {
            int row = srow + (q << 5);
            int sc = chunk ^ (row & 7);      // pre-swizzled global source, linear LDS dest
            gl_lds16(amb + (size_t)row * L + sc * 8, Ad + row * 128 + chunk * 16);
            gl_lds16(yb  + (size_t)row * L + sc * 8, Bd + row * 128 + chunk * 16);
        }
    }

    int cur = 0;
    for (int kc = 0; kc < L; kc += 64) {
        if (kc + 64 < L) {
            char* Ad = (char*)As[cur ^ 1];
            char* Bd = (char*)Bs[cur ^ 1];
            #pragma unroll
            for (int q = 0; q < 4; ++q) {
                int row = srow + (q << 5);
                int sc = chunk ^ (row & 7);
                gl_lds16(amb + (size_t)row * L + kc + 64 + sc * 8, Ad + row * 128 + chunk * 16);
                gl_lds16(yb  + (size_t)row * L + kc + 64 + sc * 8, Bd + row * 128 + chunk * 16);
            }
            asm volatile("s_waitcnt vmcnt(8)" ::: "memory");   // wait tile t only
        } else {
            asm volatile("s_waitcnt vmcnt(0)" ::: "memory");
        }
        __syncthreads();

        const char* Ac = (const char*)As[cur];
        const char* Bc = (const char*)Bs[cur];
        #pragma unroll
        for (int kk = 0; kk < 2; ++kk) {
            s16x8 af[4], bg[4];
            #pragma unroll
            for (int f = 0; f < 4; ++f) {
                int ar = wr + (f << 4) + lane15;
                af[f] = *(const s16x8*)(Ac + ar * 128 + (((kk << 6) + kbyte) ^ swa));
                int br = wc + (f << 4) + lane15;
                bg[f] = *(const s16x8*)(Bc + br * 128 + (((kk << 6) + kbyte) ^ swa));
            }
            #pragma unroll
            for (int fm = 0; fm < 4; ++fm)
                #pragma unroll
                for (int fn = 0; fn < 4; ++fn)
                    acc[fm][fn] = __builtin_amdgcn_mfma_f32_16x16x32_bf16(af[fm], bg[fn], acc[fm][fn], 0, 0, 0);
        }
        __syncthreads();
        cur ^= 1;
    }

    int col = lane15;
    int r0 = (lane >> 4) << 2;
    size_t bL = (size_t)b * L;
    #pragma unroll
    for (int fm = 0; fm < 4; ++fm) {
        #pragma unroll
        for (int j = 0; j < 4; ++j) {
            int gi = brow + wr + (fm << 4) + r0 + j;
            float rsi = rs[bL + gi];
            float rfi = rself[bL + gi];
            const unsigned short* xrow = xb + (bL + gi) * (size_t)D;
            unsigned short* orow = aggh + (bL + gi) * (size_t)D;
            #pragma unroll
            for (int fn = 0; fn < 4; ++fn) {
                int gd = bcol + wc + (fn << 4) + col;
                float v = rsi * acc[fm][fn][j] + rfi * bf2f(xrow[gd]);
                unsigned ua = __builtin_bit_cast(unsigned, v);
                ua += 0x7fffu + ((ua >> 16) & 1u);
                orow[gd] = (unsigned short)(ua >> 16);
            }
        }
    }
}

// ---------------- K4: out = LN(x + relu(agg @ W^T + b) * D^-0.5) ----------------
// BM=64 x BN=512 (full rows), grid 256 = 1 block/CU; 4 waves, wave tile 64x128.
__global__ __launch_bounds__(256) void k_linln(
    const unsigned short* __restrict__ aggh,
    const unsigned short* __restrict__ Wh,
    const float* __restrict__ bias,
    const unsigned short* __restrict__ xb,
    const float* __restrict__ lnw,
    const float* __restrict__ lnb,
    float* __restrict__ out)
{
    const int D = 512;
    __shared__ __align__(16) unsigned short As[64 * 64];    // 8KB
    __shared__ __align__(16) unsigned short Bs[512 * 64];   // 64KB
    __shared__ float psum[64][4], psq[64][4];

    int i0 = blockIdx.x << 6;
    int t = threadIdx.x;
    int lane = t & 63;
    int w = t >> 6;
    int wcol = w << 7;               // wave column base (0,128,256,384)

    int lrow8 = lane >> 3;           // 0..7
    int lchk  = lane & 7;
    char* Ac = (char*)As;
    char* Bc = (char*)Bs;

    f32x4 acc[4][8];
    #pragma unroll
    for (int i = 0; i < 4; ++i)
        #pragma unroll
        for (int j = 0; j < 8; ++j)
            acc[i][j] = (f32x4){0.f, 0.f, 0.f, 0.f};

    const int lane15 = lane & 15;
    const int kbyte = (lane >> 4) << 4;
    const int swa = (lane & 7) << 4;

    for (int kc = 0; kc < D; kc += 64) {
        // A: 64 rows of aggh; wave w stages rows w*16..w*16+15 in 2 issues of 8 rows
        // (dest = wave-uniform base + lane*16 -- required by global_load_lds)
        #pragma unroll
        for (int q = 0; q < 2; ++q) {
            int row = (w << 4) + (q << 3) + lrow8;
            int sc = lchk ^ (row & 7);
            gl_lds16(aggh + (size_t)(i0 + row) * D + kc + sc * 8,
                     Ac + row * 128 + lchk * 16);
        }
        #pragma unroll
        for (int q = 0; q < 16; ++q) {   // B: all 512 rows of Wh; row = w*8+lrow8+q*32 (lane-linear)
            int row = (w << 3) + lrow8 + (q << 5);
            int sc = lchk ^ (row & 7);
            gl_lds16(Wh + (size_t)row * D + kc + sc * 8, Bc + row * 128 + lchk * 16);
        }
        asm volatile("s_waitcnt vmcnt(0)" ::: "memory");
        __syncthreads();
        #pragma unroll
        for (int kk = 0; kk < 2; ++kk) {
            s16x8 af[4], bg[8];
            #pragma unroll
            for (int f = 0; f < 4; ++f) {
                int ar = (f << 4) + lane15;
                af[f] = *(const s16x8*)(Ac + ar * 128 + (((kk << 6) + kbyte) ^ ((ar & 7) << 4)));
            }
            #pragma unroll
            for (int f = 0; f < 8; ++f) {
                int br = wcol + (f << 4) + lane15;
                bg[f] = *(const s16x8*)(Bc + br * 128 + (((kk << 6) + kbyte) ^ swa));
            }
            #pragma unroll
            for (int fm = 0; fm < 4; ++fm)
                #pragma unroll
                for (int fn = 0; fn < 8; ++fn)
                    acc[fm][fn] = __builtin_amdgcn_mfma_f32_16x16x32_bf16(af[fm], bg[fn], acc[fm][fn], 0, 0, 0);
        }
        __syncthreads();
    }

    // epilogue: h = x + relu(acc + b)*scale, then LN over full rows
    const float scale = 0.044194173824159216f;   // 512^-0.5
    float bi[8], lw[8], lb[8];
    #pragma unroll
    for (int fn = 0; fn < 8; ++fn) {
        int colg = wcol + (fn << 4) + lane15;
        bi[fn] = bias[colg];
        lw[fn] = lnw[colg];
        lb[fn] = lnb[colg];
    }
    int r0 = (lane >> 4) << 2;
    #pragma unroll
    for (int fm = 0; fm < 4; ++fm) {
        #pragma unroll
        for (int j = 0; j < 4; ++j) {
            int r = (fm << 4) + r0 + j;
            const unsigned short* xrow = xb + (size_t)(i0 + r) * D;
            float s = 0.f, q = 0.f;
            #pragma unroll
            for (int fn = 0; fn < 8; ++fn) {
                int colg = wcol + (fn << 4) + lane15;
                float v = fmaxf(acc[fm][fn][j] + bi[fn], 0.f) * scale + bf2f(xrow[colg]);
                acc[fm][fn][j] = v;
                s += v;
                q += v * v;
            }
            #pragma unroll
            for (int m = 1; m < 16; m <<= 1) {
                s += __shfl_xor(s, m);
                q += __shfl_xor(q, m);
            }
            if (lane15 == 0) { psum[r][w] = s; psq[r][w] = q; }
        }
    }
    __syncthreads();
    #pragma unroll
    for (int fm = 0; fm < 4; ++fm) {
        #pragma unroll
        for (int j = 0; j < 4; ++j) {
            int r = (fm << 4) + r0 + j;
            float s = psum[r][0] + psum[r][1] + psum[r][2] + psum[r][3];
            float q = psq[r][0] + psq[r][1] + psq[r][2] + psq[r][3];
            float mu = s * (1.f / 512.f);
            float var = q * (1.f / 512.f) - mu * mu;
            float rstd = rsqrtf(var + LN_EPS);
            float* orow = out + (size_t)(i0 + r) * D;
            #pragma unroll
            for (int fn = 0; fn < 8; ++fn) {
                int colg = wcol + (fn << 4) + lane15;
                orow[colg] = lw[fn] * (acc[fm][fn][j] - mu) * rstd + lb[fn];
            }
        }
    }
}

extern "C" void kernel_launch(void* const* d_in, const int* in_sizes, int n_in,
                              void* d_out, int out_size, void* d_ws, size_t ws_size,
                              hipStream_t stream) {
    const float* x    = (const float*)d_in[0];
    const float* adj  = (const float*)d_in[1];
    const int*   pm   = (const int*)d_in[2];
    const float* W    = (const float*)d_in[3];
    const float* bias = (const float*)d_in[4];
    const float* lnw  = (const float*)d_in[5];
    const float* lnb  = (const float*)d_in[6];
    const float* ew   = (const float*)d_in[7];

    int BL = in_sizes[2];                 // B*L = 16384
    int L  = in_sizes[1] / BL;            // 2048
    int B  = BL / L;                      // 8
    int D  = in_sizes[0] / BL;            // 512

    char* ws = (char*)d_ws;
    size_t off = 0;
    float* dis   = (float*)(ws + off); off += (size_t)BL * 4;
    float* rs    = (float*)(ws + off); off += (size_t)BL * 4;
    float* rself = (float*)(ws + off); off += (size_t)BL * 4;
    unsigned short* am   = (unsigned short*)(ws + off); off += (size_t)BL * L * 2;
    unsigned short* yht  = (unsigned short*)(ws + off); off += (size_t)BL * D * 2;
    unsigned short* Wh   = (unsigned short*)(ws + off); off += (size_t)D * D * 2;
    unsigned short* aggh = (unsigned short*)(ws + off); off += (size_t)BL * D * 2;
    unsigned short* xb   = (unsigned short*)(ws + off); off += (size_t)BL * D * 2;

    float* out = (float*)d_out;

    k_deg<<<BL, 256, 0, stream>>>(adj, pm, ew, dis, rs, rself, am, L);
    k_xt<<<dim3(L / 64 + 1, D / 64, B), 256, 0, stream>>>(x, dis, W, yht, xb, Wh, L, D);
    k_aggmm<<<B * (L / 128) * (D / 128), 256, 0, stream>>>(am, yht, xb, rs, rself, aggh, L, D);
    k_linln<<<BL / 64, 256, 0, stream>>>(aggh, Wh, bias, xb, lnw, lnb, out);
}

// Round 8
// 117.697 us; speedup vs baseline: 1.0601x; 1.0601x over previous
//
#include <hip/hip_runtime.h>

#define LN_EPS 1e-5f

typedef __attribute__((ext_vector_type(8))) short s16x8;
typedef __attribute__((ext_vector_type(4))) float f32x4;

__device__ inline unsigned int pk_bf16(float a, float b) {
    unsigned ua = __builtin_bit_cast(unsigned, a);
    unsigned ub = __builtin_bit_cast(unsigned, b);
    ua += 0x7fffu + ((ua >> 16) & 1u);
    ub += 0x7fffu + ((ub >> 16) & 1u);
    return (ua >> 16) | (ub & 0xffff0000u);
}
__device__ inline unsigned short cv_bf16(float a) {
    unsigned ua = __builtin_bit_cast(unsigned, a);
    ua += 0x7fffu + ((ua >> 16) & 1u);
    return (unsigned short)(ua >> 16);
}
__device__ inline float bf2f(unsigned short h) {
    unsigned u = ((unsigned)h) << 16;
    return __builtin_bit_cast(float, u);
}
__device__ inline void gl_lds16(const void* g, void* l) {
    __builtin_amdgcn_global_load_lds((const __attribute__((address_space(1))) void*)g,
                                     (__attribute__((address_space(3))) void*)l, 16, 0, 0);
}

// ---------------- K0: per-batch scan of valid mask -> pos, idx, cnt ----------------
__global__ __launch_bounds__(256) void k_scan(const int* __restrict__ pm,
                                              unsigned short* __restrict__ pos,
                                              unsigned short* __restrict__ idx,
                                              int* __restrict__ cnt, int L) {
    int b = blockIdx.x, t = threadIdx.x;
    const int* pmb = pm + (size_t)b * L;
    int j0 = t * 8;
    int v[8]; int s = 0;
    #pragma unroll
    for (int k = 0; k < 8; ++k) { v[k] = (pmb[j0 + k] == 0) ? 1 : 0; s += v[k]; }
    __shared__ int ps[256];
    ps[t] = s;
    __syncthreads();
    for (int off = 1; off < 256; off <<= 1) {
        int val = (t >= off) ? ps[t - off] : 0;
        __syncthreads();
        ps[t] += val;
        __syncthreads();
    }
    int base = ps[t] - s;   // exclusive prefix
    unsigned short* posb = pos + (size_t)b * L;
    unsigned short* idxb = idx + (size_t)b * L;
    #pragma unroll
    for (int k = 0; k < 8; ++k) {
        posb[j0 + k] = (unsigned short)base;
        if (v[k]) { idxb[base] = (unsigned short)(j0 + k); base++; }
    }
    if (t == 255) cnt[b] = ps[255];
}

// ---------------- K1: degree + column-compacted masked bf16 adjacency ----------------
// padded rows: dis=1, rs=0, rself=e (no adj read).
// valid rows: amc[b, pos[i], pos[j]] = bf16(adj[i,j]) for valid j; zero tail to Kc.
__global__ __launch_bounds__(256) void k_deg(const float* __restrict__ adj,
                                             const int* __restrict__ pm,
                                             const float* __restrict__ ew,
                                             const unsigned short* __restrict__ pos,
                                             const int* __restrict__ cnt,
                                             float* __restrict__ dis_o,
                                             float* __restrict__ rs,
                                             float* __restrict__ rself,
                                             unsigned short* __restrict__ amc,
                                             int L) {
    int row = blockIdx.x;
    int b = row / L;
    int i = row - b * L;
    const int* pmb = pm + (size_t)b * L;
    int t = threadIdx.x;
    float e = ew[0];
    if (pmb[i] != 0) {                  // padded row: deg = 1
        if (t == 0) { dis_o[row] = 1.f; rs[row] = 0.f; rself[row] = e; }
        return;
    }
    const float* arow = adj + (size_t)row * L;
    const unsigned short* posb = pos + (size_t)b * L;
    int rloc = posb[i];
    int cb = cnt[b];
    unsigned short* amrow = amc + ((size_t)b * L + rloc) * L;

    int j0 = t * 8;                     // one chunk per thread (L = 2048)
    float4 a0 = *(const float4*)(arow + j0);
    float4 a1 = *(const float4*)(arow + j0 + 4);
    int4 p0 = *(const int4*)(pmb + j0);
    int4 p1 = *(const int4*)(pmb + j0 + 4);
    uint4 pv = *(const uint4*)(posb + j0);
    unsigned pc0 = pv.x & 0xffffu, pc1 = pv.x >> 16;
    unsigned pc2 = pv.y & 0xffffu, pc3 = pv.y >> 16;
    unsigned pc4 = pv.z & 0xffffu, pc5 = pv.z >> 16;
    unsigned pc6 = pv.w & 0xffffu, pc7 = pv.w >> 16;
    float m0 = p0.x == 0 ? a0.x : 0.f;
    float m1 = p0.y == 0 ? a0.y : 0.f;
    float m2 = p0.z == 0 ? a0.z : 0.f;
    float m3 = p0.w == 0 ? a0.w : 0.f;
    float m4 = p1.x == 0 ? a1.x : 0.f;
    float m5 = p1.y == 0 ? a1.y : 0.f;
    float m6 = p1.z == 0 ? a1.z : 0.f;
    float m7 = p1.w == 0 ? a1.w : 0.f;
    float s = ((m0 + m1) + (m2 + m3)) + ((m4 + m5) + (m6 + m7));
    if (p0.x == 0) amrow[pc0] = cv_bf16(m0);
    if (p0.y == 0) amrow[pc1] = cv_bf16(m1);
    if (p0.z == 0) amrow[pc2] = cv_bf16(m2);
    if (p0.w == 0) amrow[pc3] = cv_bf16(m3);
    if (p1.x == 0) amrow[pc4] = cv_bf16(m4);
    if (p1.y == 0) amrow[pc5] = cv_bf16(m5);
    if (p1.z == 0) amrow[pc6] = cv_bf16(m6);
    if (p1.w == 0) amrow[pc7] = cv_bf16(m7);

    int kcap = (cb + 63) & ~63;         // zero pad tail [cb, Kc)
    for (int k = cb + t; k < kcap; k += 256) amrow[k] = 0;

    #pragma unroll
    for (int off = 32; off; off >>= 1) s += __shfl_down(s, off);
    __shared__ float wsum[4];
    if ((t & 63) == 0) wsum[t >> 6] = s;
    __syncthreads();
    if (t == 0) {
        float tot = wsum[0] + wsum[1] + wsum[2] + wsum[3];
        float d = rsqrtf(1.f + tot);
        dis_o[row]  = d;
        rs[row]     = e * d;
        rself[row]  = e * d * d;
    }
}

// ---------------- K2: xb = bf16(x) all rows; aggh = bf16(ew*x) for PADDED rows;
//                      + W->Wh convert in trailing blocks ----------------
__global__ __launch_bounds__(256) void k_xb(const float* __restrict__ x,
                                            const int* __restrict__ pm,
                                            const float* __restrict__ ew,
                                            const float* __restrict__ W,
                                            unsigned short* __restrict__ xb,
                                            unsigned short* __restrict__ aggh,
                                            unsigned short* __restrict__ Wh,
                                            int nx) {
    const int D = 512;
    int bid = blockIdx.x;
    int t = threadIdx.x;
    if (bid >= nx) {                    // W convert: 64 blocks x 256 thr x 16 elems
        int seg = bid - nx;
        int i = (seg * 256 + t) * 16;
        #pragma unroll
        for (int k = 0; k < 16; k += 4) {
            float4 v = *(const float4*)(W + i + k);
            uint2 o;
            o.x = pk_bf16(v.x, v.y);
            o.y = pk_bf16(v.z, v.w);
            *(uint2*)(Wh + i + k) = o;
        }
        return;
    }
    int gid = bid * 256 + t;            // 8-elem chunk; 64 chunks per row
    int row = gid >> 6;
    int co = (gid & 63) << 3;
    float e = ew[0];
    const float* xp = x + (size_t)row * D + co;
    float4 v0 = *(const float4*)(xp);
    float4 v1 = *(const float4*)(xp + 4);
    uint4 o;
    o.x = pk_bf16(v0.x, v0.y);
    o.y = pk_bf16(v0.z, v0.w);
    o.z = pk_bf16(v1.x, v1.y);
    o.w = pk_bf16(v1.z, v1.w);
    *(uint4*)(xb + (size_t)row * D + co) = o;
    if (pm[row] != 0) {                 // padded row: agg = ew * x  (dis=1)
        uint4 oa;
        oa.x = pk_bf16(e * v0.x, e * v0.y);
        oa.y = pk_bf16(e * v0.z, e * v0.w);
        oa.z = pk_bf16(e * v1.x, e * v1.y);
        oa.w = pk_bf16(e * v1.z, e * v1.w);
        *(uint4*)(aggh + (size_t)row * D + co) = oa;
    }
}

// ---------------- K3: compacted transpose: yc[b, d, k] = bf16(dis[idx_k] * x[idx_k, d]) ----------------
__global__ __launch_bounds__(256) void k_yt(const float* __restrict__ x,
                                            const float* __restrict__ dis,
                                            const unsigned short* __restrict__ idx,
                                            const int* __restrict__ cnt,
                                            unsigned short* __restrict__ yc,
                                            int L, int D) {
    int b = blockIdx.z;
    int kb = blockIdx.x << 6;
    int db = blockIdx.y << 6;
    int cb = cnt[b];
    if (kb >= cb) return;
    __shared__ float tile[64][65];
    int t = threadIdx.x;
    int kk = t >> 2, c4 = (t & 3) << 4;
    int kg = kb + kk;
    if (kg < cb) {
        int ol = idx[(size_t)b * L + kg];
        float dl = dis[(size_t)b * L + ol];
        const float* xp = x + ((size_t)b * L + ol) * D + db + c4;
        #pragma unroll
        for (int k = 0; k < 16; k += 4) {
            float4 v = *(const float4*)(xp + k);
            tile[kk][c4 + k + 0] = v.x * dl;
            tile[kk][c4 + k + 1] = v.y * dl;
            tile[kk][c4 + k + 2] = v.z * dl;
            tile[kk][c4 + k + 3] = v.w * dl;
        }
    } else {
        #pragma unroll
        for (int k = 0; k < 16; ++k) tile[kk][c4 + k] = 0.f;
    }
    __syncthreads();
    int dr = t >> 2, k0 = (t & 3) << 4;
    unsigned short* op = yc + ((size_t)b * D + db + dr) * L + kb + k0;
    uint4 o0, o1;
    o0.x = pk_bf16(tile[k0 + 0][dr],  tile[k0 + 1][dr]);
    o0.y = pk_bf16(tile[k0 + 2][dr],  tile[k0 + 3][dr]);
    o0.z = pk_bf16(tile[k0 + 4][dr],  tile[k0 + 5][dr]);
    o0.w = pk_bf16(tile[k0 + 6][dr],  tile[k0 + 7][dr]);
    o1.x = pk_bf16(tile[k0 + 8][dr],  tile[k0 + 9][dr]);
    o1.y = pk_bf16(tile[k0 + 10][dr], tile[k0 + 11][dr]);
    o1.z = pk_bf16(tile[k0 + 12][dr], tile[k0 + 13][dr]);
    o1.w = pk_bf16(tile[k0 + 14][dr], tile[k0 + 15][dr]);
    *(uint4*)(op) = o0;
    *(uint4*)(op + 8) = o1;
}

// ---------------- K4: compacted GEMM: agg[idx_i] = rs_i*(amc @ yc) + rself_i*x ----------------
// MFMA bf16; BM=BN=128, BK=64; 4 waves of 64x64; dbuf + counted vmcnt; early-exit tiles.
__global__ __launch_bounds__(256, 2) void k_aggmm(
    const unsigned short* __restrict__ amc,
    const unsigned short* __restrict__ yc,
    const unsigned short* __restrict__ xb,
    const float* __restrict__ rs,
    const float* __restrict__ rself,
    const unsigned short* __restrict__ idx,
    const int* __restrict__ cnt,
    unsigned short* __restrict__ aggh,
    int L, int D)
{
    __shared__ __align__(16) unsigned short As[2][128 * 64];
    __shared__ __align__(16) unsigned short Bs[2][128 * 64];
    int bid = blockIdx.x;
    int wid = (bid & 7) * 64 + (bid >> 3);   // one batch per XCD (512 = 8*64, bijective)
    int b   = wid >> 6;
    int t6  = wid & 63;
    int brow = (t6 >> 2) << 7;               // compacted row base
    int bcol = (t6 & 3) << 7;

    int Mc = cnt[b];
    if (brow >= Mc) return;                  // uniform early-exit (before any barrier)
    int Kc = (Mc + 63) & ~63;

    int t = threadIdx.x;
    int lane = t & 63;
    int w = t >> 6;
    int wr = ((w >> 1) & 1) << 6;
    int wc = (w & 1) << 6;

    const unsigned short* amb = amc + ((size_t)b * L + brow) * L;
    const unsigned short* yb  = yc + ((size_t)b * D + bcol) * L;
    const unsigned short* idxb = idx + (size_t)b * L;

    int srow = t >> 3;          // 0..31 (lane-linear dest)
    int chunk = t & 7;

    f32x4 acc[4][4];
    #pragma unroll
    for (int i = 0; i < 4; ++i)
        #pragma unroll
        for (int j = 0; j < 4; ++j)
            acc[i][j] = (f32x4){0.f, 0.f, 0.f, 0.f};

    const int lane15 = lane & 15;
    const int kbyte = (lane >> 4) << 4;
    const int swa = (lane & 7) << 4;

    {
        char* Ad = (char*)As[0];
        char* Bd = (char*)Bs[0];
        #pragma unroll
        for (int q = 0; q < 4; ++q) {
            int row = srow + (q << 5);
            int sc = chunk ^ (row & 7);      // pre-swizzled global source, linear LDS dest
            gl_lds16(amb + (size_t)row * L + sc * 8, Ad + row * 128 + chunk * 16);
            gl_lds16(yb  + (size_t)row * L + sc * 8, Bd + row * 128 + chunk * 16);
        }
    }

    int cur = 0;
    for (int kc = 0; kc < Kc; kc += 64) {
        if (kc + 64 < Kc) {
            char* Ad = (char*)As[cur ^ 1];
            char* Bd = (char*)Bs[cur ^ 1];
            #pragma unroll
            for (int q = 0; q < 4; ++q) {
                int row = srow + (q << 5);
                int sc = chunk ^ (row & 7);
                gl_lds16(amb + (size_t)row * L + kc + 64 + sc * 8, Ad + row * 128 + chunk * 16);
                gl_lds16(yb  + (size_t)row * L + kc + 64 + sc * 8, Bd + row * 128 + chunk * 16);
            }
            asm volatile("s_waitcnt vmcnt(8)" ::: "memory");
        } else {
            asm volatile("s_waitcnt vmcnt(0)" ::: "memory");
        }
        __syncthreads();

        const char* Ac = (const char*)As[cur];
        const char* Bc = (const char*)Bs[cur];
        #pragma unroll
        for (int kk = 0; kk < 2; ++kk) {
            s16x8 af[4], bg[4];
            #pragma unroll
            for (int f = 0; f < 4; ++f) {
                int ar = wr + (f << 4) + lane15;
                af[f] = *(const s16x8*)(Ac + ar * 128 + (((kk << 6) + kbyte) ^ swa));
                int br = wc + (f << 4) + lane15;
                bg[f] = *(const s16x8*)(Bc + br * 128 + (((kk << 6) + kbyte) ^ swa));
            }
            #pragma unroll
            for (int fm = 0; fm < 4; ++fm)
                #pragma unroll
                for (int fn = 0; fn < 4; ++fn)
                    acc[fm][fn] = __builtin_amdgcn_mfma_f32_16x16x32_bf16(af[fm], bg[fn], acc[fm][fn], 0, 0, 0);
        }
        __syncthreads();
        cur ^= 1;
    }

    int col = lane15;
    int r0 = (lane >> 4) << 2;
    size_t bL = (size_t)b * L;
    #pragma unroll
    for (int fm = 0; fm < 4; ++fm) {
        #pragma unroll
        for (int j = 0; j < 4; ++j) {
            int rcmp = brow + wr + (fm << 4) + r0 + j;
            if (rcmp < Mc) {
                int gi = idxb[rcmp];
                float rsi = rs[bL + gi];
                float rfi = rself[bL + gi];
                const unsigned short* xrow = xb + (bL + gi) * (size_t)D;
                unsigned short* orow = aggh + (bL + gi) * (size_t)D;
                #pragma unroll
                for (int fn = 0; fn < 4; ++fn) {
                    int gd = bcol + wc + (fn << 4) + col;
                    float v = rsi * acc[fm][fn][j] + rfi * bf2f(xrow[gd]);
                    orow[gd] = cv_bf16(v);
                }
            }
        }
    }
}

// ---------------- K5: out = LN(x + relu(agg @ W^T + b) * D^-0.5)  (BM=32 x BN=512) ----------------
__global__ __launch_bounds__(256, 2) void k_linln(
    const unsigned short* __restrict__ aggh,
    const unsigned short* __restrict__ Wh,
    const float* __restrict__ bias,
    const unsigned short* __restrict__ xb,
    const float* __restrict__ lnw,
    const float* __restrict__ lnb,
    float* __restrict__ out)
{
    const int D = 512;
    __shared__ __align__(16) unsigned short As[32 * 64];    // 4KB
    __shared__ __align__(16) unsigned short Bs[512 * 64];   // 64KB
    __shared__ float psum[32][4], psq[32][4];

    int i0 = blockIdx.x << 5;
    int t = threadIdx.x;
    int lane = t & 63;
    int w = t >> 6;
    int wcol = w << 7;

    int srow = t >> 3;               // 0..31 (lane-linear dest)
    int chunk = t & 7;
    char* Ac = (char*)As;
    char* Bc = (char*)Bs;

    f32x4 acc[2][8];
    #pragma unroll
    for (int i = 0; i < 2; ++i)
        #pragma unroll
        for (int j = 0; j < 8; ++j)
            acc[i][j] = (f32x4){0.f, 0.f, 0.f, 0.f};

    const int lane15 = lane & 15;
    const int kbyte = (lane >> 4) << 4;
    const int swa = (lane & 7) << 4;

    for (int kc = 0; kc < D; kc += 64) {
        {   // A: 32 rows of aggh
            int sc = chunk ^ (srow & 7);
            gl_lds16(aggh + (size_t)(i0 + srow) * D + kc + sc * 8, Ac + srow * 128 + chunk * 16);
        }
        #pragma unroll
        for (int q = 0; q < 16; ++q) {   // B: all 512 rows of Wh
            int row = srow + (q << 5);
            int sc = chunk ^ (row & 7);
            gl_lds16(Wh + (size_t)row * D + kc + sc * 8, Bc + row * 128 + chunk * 16);
        }
        asm volatile("s_waitcnt vmcnt(0)" ::: "memory");
        __syncthreads();
        #pragma unroll
        for (int kk = 0; kk < 2; ++kk) {
            s16x8 af[2], bg[8];
            #pragma unroll
            for (int f = 0; f < 2; ++f) {
                int ar = (f << 4) + lane15;
                af[f] = *(const s16x8*)(Ac + ar * 128 + (((kk << 6) + kbyte) ^ ((ar & 7) << 4)));
            }
            #pragma unroll
            for (int f = 0; f < 8; ++f) {
                int br = wcol + (f << 4) + lane15;
                bg[f] = *(const s16x8*)(Bc + br * 128 + (((kk << 6) + kbyte) ^ swa));
            }
            #pragma unroll
            for (int fm = 0; fm < 2; ++fm)
                #pragma unroll
                for (int fn = 0; fn < 8; ++fn)
                    acc[fm][fn] = __builtin_amdgcn_mfma_f32_16x16x32_bf16(af[fm], bg[fn], acc[fm][fn], 0, 0, 0);
        }
        __syncthreads();
    }

    const float scale = 0.044194173824159216f;   // 512^-0.5
    float bi[8], lw[8], lb[8];
    #pragma unroll
    for (int fn = 0; fn < 8; ++fn) {
        int colg = wcol + (fn << 4) + lane15;
        bi[fn] = bias[colg];
        lw[fn] = lnw[colg];
        lb[fn] = lnb[colg];
    }
    int r0 = (lane >> 4) << 2;
    #pragma unroll
    for (int fm = 0; fm < 2; ++fm) {
        #pragma unroll
        for (int j = 0; j < 4; ++j) {
            int r = (fm << 4) + r0 + j;
            const unsigned short* xrow = xb + (size_t)(i0 + r) * D;
            float s = 0.f, q = 0.f;
            #pragma unroll
            for (int fn = 0; fn < 8; ++fn) {
                int colg = wcol + (fn << 4) + lane15;
                float v = fmaxf(acc[fm][fn][j] + bi[fn], 0.f) * scale + bf2f(xrow[colg]);
                acc[fm][fn][j] = v;
                s += v;
                q += v * v;
            }
            #pragma unroll
            for (int m = 1; m < 16; m <<= 1) {
                s += __shfl_xor(s, m);
                q += __shfl_xor(q, m);
            }
            if (lane15 == 0) { psum[r][w] = s; psq[r][w] = q; }
        }
    }
    __syncthreads();
    #pragma unroll
    for (int fm = 0; fm < 2; ++fm) {
        #pragma unroll
        for (int j = 0; j < 4; ++j) {
            int r = (fm << 4) + r0 + j;
            float s = psum[r][0] + psum[r][1] + psum[r][2] + psum[r][3];
            float q = psq[r][0] + psq[r][1] + psq[r][2] + psq[r][3];
            float mu = s * (1.f / 512.f);
            float var = q * (1.f / 512.f) - mu * mu;
            float rstd = rsqrtf(var + LN_EPS);
            float* orow = out + (size_t)(i0 + r) * D;
            #pragma unroll
            for (int fn = 0; fn < 8; ++fn) {
                int colg = wcol + (fn << 4) + lane15;
                orow[colg] = lw[fn] * (acc[fm][fn][j] - mu) * rstd + lb[fn];
            }
        }
    }
}

extern "C" void kernel_launch(void* const* d_in, const int* in_sizes, int n_in,
                              void* d_out, int out_size, void* d_ws, size_t ws_size,
                              hipStream_t stream) {
    const float* x    = (const float*)d_in[0];
    const float* adj  = (const float*)d_in[1];
    const int*   pm   = (const int*)d_in[2];
    const float* W    = (const float*)d_in[3];
    const float* bias = (const float*)d_in[4];
    const float* lnw  = (const float*)d_in[5];
    const float* lnb  = (const float*)d_in[6];
    const float* ew   = (const float*)d_in[7];

    int BL = in_sizes[2];                 // B*L = 16384
    int L  = in_sizes[1] / BL;            // 2048
    int B  = BL / L;                      // 8
    int D  = in_sizes[0] / BL;            // 512

    char* ws = (char*)d_ws;
    size_t off = 0;
    float* dis   = (float*)(ws + off); off += (size_t)BL * 4;
    float* rs    = (float*)(ws + off); off += (size_t)BL * 4;
    float* rself = (float*)(ws + off); off += (size_t)BL * 4;
    unsigned short* pos = (unsigned short*)(ws + off); off += (size_t)BL * 2;
    unsigned short* idx = (unsigned short*)(ws + off); off += (size_t)BL * 2;
    int* cnt = (int*)(ws + off); off += 64;
    unsigned short* amc  = (unsigned short*)(ws + off); off += (size_t)BL * L * 2;
    unsigned short* yc   = (unsigned short*)(ws + off); off += (size_t)BL * D * 2;
    unsigned short* Wh   = (unsigned short*)(ws + off); off += (size_t)D * D * 2;
    unsigned short* aggh = (unsigned short*)(ws + off); off += (size_t)BL * D * 2;
    unsigned short* xb   = (unsigned short*)(ws + off); off += (size_t)BL * D * 2;

    float* out = (float*)d_out;
    int nx = (BL * D) / (256 * 8);        // 4096 data blocks for k_xb

    k_scan<<<B, 256, 0, stream>>>(pm, pos, idx, cnt, L);
    k_deg<<<BL, 256, 0, stream>>>(adj, pm, ew, pos, cnt, dis, rs, rself, amc, L);
    k_xb<<<nx + (D * D) / (256 * 16), 256, 0, stream>>>(x, pm, ew, W, xb, aggh, Wh, nx);
    k_yt<<<dim3(L / 64, D / 64, B), 256, 0, stream>>>(x, dis, idx, cnt, yc, L, D);
    k_aggmm<<<B * (L / 128) * (D / 128), 256, 0, stream>>>(amc, yc, xb, rs, rself, idx, cnt, aggh, L, D);
    k_linln<<<BL / 32, 256, 0, stream>>>(aggh, Wh, bias, xb, lnw, lnb, out);
}

// Round 9
// 106.046 us; speedup vs baseline: 1.1766x; 1.1099x over previous
//
#include <hip/hip_runtime.h>

#define LN_EPS 1e-5f

typedef __attribute__((ext_vector_type(8))) short s16x8;
typedef __attribute__((ext_vector_type(4))) float f32x4;

__device__ inline unsigned int pk_bf16(float a, float b) {
    unsigned ua = __builtin_bit_cast(unsigned, a);
    unsigned ub = __builtin_bit_cast(unsigned, b);
    ua += 0x7fffu + ((ua >> 16) & 1u);
    ub += 0x7fffu + ((ub >> 16) & 1u);
    return (ua >> 16) | (ub & 0xffff0000u);
}
__device__ inline unsigned short cv_bf16(float a) {
    unsigned ua = __builtin_bit_cast(unsigned, a);
    ua += 0x7fffu + ((ua >> 16) & 1u);
    return (unsigned short)(ua >> 16);
}
__device__ inline float bf2f(unsigned short h) {
    unsigned u = ((unsigned)h) << 16;
    return __builtin_bit_cast(float, u);
}
__device__ inline void gl_lds16(const void* g, void* l) {
    __builtin_amdgcn_global_load_lds((const __attribute__((address_space(1))) void*)g,
                                     (__attribute__((address_space(3))) void*)l, 16, 0, 0);
}

// ---------------- K0: per-batch scan of valid mask -> pos, idx, cnt ----------------
__global__ __launch_bounds__(256) void k_scan(const int* __restrict__ pm,
                                              unsigned short* __restrict__ pos,
                                              unsigned short* __restrict__ idx,
                                              int* __restrict__ cnt, int L) {
    int b = blockIdx.x, t = threadIdx.x;
    const int* pmb = pm + (size_t)b * L;
    int j0 = t * 8;
    int v[8]; int s = 0;
    #pragma unroll
    for (int k = 0; k < 8; ++k) { v[k] = (pmb[j0 + k] == 0) ? 1 : 0; s += v[k]; }
    __shared__ int ps[256];
    ps[t] = s;
    __syncthreads();
    for (int off = 1; off < 256; off <<= 1) {
        int val = (t >= off) ? ps[t - off] : 0;
        __syncthreads();
        ps[t] += val;
        __syncthreads();
    }
    int base = ps[t] - s;   // exclusive prefix
    unsigned short* posb = pos + (size_t)b * L;
    unsigned short* idxb = idx + (size_t)b * L;
    #pragma unroll
    for (int k = 0; k < 8; ++k) {
        posb[j0 + k] = (unsigned short)base;
        if (v[k]) { idxb[base] = (unsigned short)(j0 + k); base++; }
    }
    if (t == 255) cnt[b] = ps[255];
}

// ---------------- K1: degree + column-compacted masked bf16 adjacency ----------------
// padded rows: dis=1, rs=0, rself=e (no adj read).
// valid rows: LDS-stage compacted row, then coalesced uint4 writes.
__global__ __launch_bounds__(256) void k_deg(const float* __restrict__ adj,
                                             const int* __restrict__ pm,
                                             const float* __restrict__ ew,
                                             const unsigned short* __restrict__ pos,
                                             const int* __restrict__ cnt,
                                             float* __restrict__ dis_o,
                                             float* __restrict__ rs,
                                             float* __restrict__ rself,
                                             unsigned short* __restrict__ amc,
                                             int L) {
    int row = blockIdx.x;
    int b = row / L;
    int i = row - b * L;
    const int* pmb = pm + (size_t)b * L;
    int t = threadIdx.x;
    float e = ew[0];
    if (pmb[i] != 0) {                  // padded row: deg = 1
        if (t == 0) { dis_o[row] = 1.f; rs[row] = 0.f; rself[row] = e; }
        return;
    }
    __shared__ unsigned short ls[2048 + 64];
    __shared__ float wsum[4];
    const float* arow = adj + (size_t)row * L;
    const unsigned short* posb = pos + (size_t)b * L;
    int rloc = posb[i];
    int cb = cnt[b];
    int kcap = (cb + 63) & ~63;

    // zero pad tail of staged row
    for (int k = cb + t; k < kcap; k += 256) ls[k] = 0;

    int j0 = t * 8;                     // one chunk per thread (L = 2048)
    float4 a0 = *(const float4*)(arow + j0);
    float4 a1 = *(const float4*)(arow + j0 + 4);
    int4 p0 = *(const int4*)(pmb + j0);
    int4 p1 = *(const int4*)(pmb + j0 + 4);
    uint4 pv = *(const uint4*)(posb + j0);
    unsigned pc0 = pv.x & 0xffffu, pc1 = pv.x >> 16;
    unsigned pc2 = pv.y & 0xffffu, pc3 = pv.y >> 16;
    unsigned pc4 = pv.z & 0xffffu, pc5 = pv.z >> 16;
    unsigned pc6 = pv.w & 0xffffu, pc7 = pv.w >> 16;
    float m0 = p0.x == 0 ? a0.x : 0.f;
    float m1 = p0.y == 0 ? a0.y : 0.f;
    float m2 = p0.z == 0 ? a0.z : 0.f;
    float m3 = p0.w == 0 ? a0.w : 0.f;
    float m4 = p1.x == 0 ? a1.x : 0.f;
    float m5 = p1.y == 0 ? a1.y : 0.f;
    float m6 = p1.z == 0 ? a1.z : 0.f;
    float m7 = p1.w == 0 ? a1.w : 0.f;
    float s = ((m0 + m1) + (m2 + m3)) + ((m4 + m5) + (m6 + m7));
    if (p0.x == 0) ls[pc0] = cv_bf16(m0);
    if (p0.y == 0) ls[pc1] = cv_bf16(m1);
    if (p0.z == 0) ls[pc2] = cv_bf16(m2);
    if (p0.w == 0) ls[pc3] = cv_bf16(m3);
    if (p1.x == 0) ls[pc4] = cv_bf16(m4);
    if (p1.y == 0) ls[pc5] = cv_bf16(m5);
    if (p1.z == 0) ls[pc6] = cv_bf16(m6);
    if (p1.w == 0) ls[pc7] = cv_bf16(m7);

    #pragma unroll
    for (int off = 32; off; off >>= 1) s += __shfl_down(s, off);
    if ((t & 63) == 0) wsum[t >> 6] = s;
    __syncthreads();

    // coalesced write-out of compacted row
    unsigned short* amrow = amc + ((size_t)b * L + rloc) * L;
    if (j0 < kcap) *(uint4*)(amrow + j0) = *(const uint4*)(ls + j0);

    if (t == 0) {
        float tot = wsum[0] + wsum[1] + wsum[2] + wsum[3];
        float d = rsqrtf(1.f + tot);
        dis_o[row]  = d;
        rs[row]     = e * d;
        rself[row]  = e * d * d;
    }
}

// ---------------- K2: xb = bf16(x) all rows; aggh = bf16(ew*x) for PADDED rows;
//                      + W->Wh convert in trailing blocks ----------------
__global__ __launch_bounds__(256) void k_xb(const float* __restrict__ x,
                                            const int* __restrict__ pm,
                                            const float* __restrict__ ew,
                                            const float* __restrict__ W,
                                            unsigned short* __restrict__ xb,
                                            unsigned short* __restrict__ aggh,
                                            unsigned short* __restrict__ Wh,
                                            int nx) {
    const int D = 512;
    int bid = blockIdx.x;
    int t = threadIdx.x;
    if (bid >= nx) {                    // W convert: 64 blocks x 256 thr x 16 elems
        int seg = bid - nx;
        int i = (seg * 256 + t) * 16;
        #pragma unroll
        for (int k = 0; k < 16; k += 4) {
            float4 v = *(const float4*)(W + i + k);
            uint2 o;
            o.x = pk_bf16(v.x, v.y);
            o.y = pk_bf16(v.z, v.w);
            *(uint2*)(Wh + i + k) = o;
        }
        return;
    }
    int gid = bid * 256 + t;            // 8-elem chunk; 64 chunks per row
    int row = gid >> 6;
    int co = (gid & 63) << 3;
    float e = ew[0];
    const float* xp = x + (size_t)row * D + co;
    float4 v0 = *(const float4*)(xp);
    float4 v1 = *(const float4*)(xp + 4);
    uint4 o;
    o.x = pk_bf16(v0.x, v0.y);
    o.y = pk_bf16(v0.z, v0.w);
    o.z = pk_bf16(v1.x, v1.y);
    o.w = pk_bf16(v1.z, v1.w);
    *(uint4*)(xb + (size_t)row * D + co) = o;
    if (pm[row] != 0) {                 // padded row: agg = ew * x  (dis=1)
        uint4 oa;
        oa.x = pk_bf16(e * v0.x, e * v0.y);
        oa.y = pk_bf16(e * v0.z, e * v0.w);
        oa.z = pk_bf16(e * v1.x, e * v1.y);
        oa.w = pk_bf16(e * v1.z, e * v1.w);
        *(uint4*)(aggh + (size_t)row * D + co) = oa;
    }
}

// ---------------- K3: compacted transpose: yc[b, d, k] = bf16(dis[idx_k] * x[idx_k, d]) ----------------
__global__ __launch_bounds__(256) void k_yt(const float* __restrict__ x,
                                            const float* __restrict__ dis,
                                            const unsigned short* __restrict__ idx,
                                            const int* __restrict__ cnt,
                                            unsigned short* __restrict__ yc,
                                            int L, int D) {
    int b = blockIdx.z;
    int kb = blockIdx.x << 6;
    int db = blockIdx.y << 6;
    int cb = cnt[b];
    if (kb >= cb) return;
    __shared__ float tile[64][65];
    int t = threadIdx.x;
    int kk = t >> 2, c4 = (t & 3) << 4;
    int kg = kb + kk;
    if (kg < cb) {
        int ol = idx[(size_t)b * L + kg];
        float dl = dis[(size_t)b * L + ol];
        const float* xp = x + ((size_t)b * L + ol) * D + db + c4;
        #pragma unroll
        for (int k = 0; k < 16; k += 4) {
            float4 v = *(const float4*)(xp + k);
            tile[kk][c4 + k + 0] = v.x * dl;
            tile[kk][c4 + k + 1] = v.y * dl;
            tile[kk][c4 + k + 2] = v.z * dl;
            tile[kk][c4 + k + 3] = v.w * dl;
        }
    } else {
        #pragma unroll
        for (int k = 0; k < 16; ++k) tile[kk][c4 + k] = 0.f;
    }
    __syncthreads();
    int dr = t >> 2, k0 = (t & 3) << 4;
    unsigned short* op = yc + ((size_t)b * D + db + dr) * L + kb + k0;
    uint4 o0, o1;
    o0.x = pk_bf16(tile[k0 + 0][dr],  tile[k0 + 1][dr]);
    o0.y = pk_bf16(tile[k0 + 2][dr],  tile[k0 + 3][dr]);
    o0.z = pk_bf16(tile[k0 + 4][dr],  tile[k0 + 5][dr]);
    o0.w = pk_bf16(tile[k0 + 6][dr],  tile[k0 + 7][dr]);
    o1.x = pk_bf16(tile[k0 + 8][dr],  tile[k0 + 9][dr]);
    o1.y = pk_bf16(tile[k0 + 10][dr], tile[k0 + 11][dr]);
    o1.z = pk_bf16(tile[k0 + 12][dr], tile[k0 + 13][dr]);
    o1.w = pk_bf16(tile[k0 + 14][dr], tile[k0 + 15][dr]);
    *(uint4*)(op) = o0;
    *(uint4*)(op + 8) = o1;
}

// ---------------- K4: compacted GEMM: agg[idx_i] = rs_i*(amc @ yc) + rself_i*x ----------------
// MFMA bf16; BM=64, BN=128, BK=64; 4 waves of 32x64; single-buffer 24KB LDS.
// ~512 active blocks (2/CU) after early-exit -> co-resident overlap restored.
__global__ __launch_bounds__(256) void k_aggmm(
    const unsigned short* __restrict__ amc,
    const unsigned short* __restrict__ yc,
    const unsigned short* __restrict__ xb,
    const float* __restrict__ rs,
    const float* __restrict__ rself,
    const unsigned short* __restrict__ idx,
    const int* __restrict__ cnt,
    unsigned short* __restrict__ aggh,
    int L, int D)
{
    __shared__ __align__(16) unsigned short As[64 * 64];    // 8KB
    __shared__ __align__(16) unsigned short Bs[128 * 64];   // 16KB
    int bid = blockIdx.x;
    int wid = (bid & 7) * 128 + (bid >> 3);  // 1024 = 8*128, bijective; one batch per XCD
    int b   = wid >> 7;
    int t6  = wid & 127;
    int brow = (t6 >> 2) << 6;               // compacted row base (32 row-blocks)
    int bcol = (t6 & 3) << 7;

    int Mc = cnt[b];
    if (brow >= Mc) return;                  // uniform early-exit (before any barrier)
    int Kc = (Mc + 63) & ~63;

    int t = threadIdx.x;
    int lane = t & 63;
    int w = t >> 6;
    int wr = ((w >> 1) & 1) << 5;            // 0 or 32
    int wc = (w & 1) << 6;                   // 0 or 64

    const unsigned short* amb = amc + ((size_t)b * L + brow) * L;
    const unsigned short* yb  = yc + ((size_t)b * D + bcol) * L;
    const unsigned short* idxb = idx + (size_t)b * L;

    int lr8 = lane >> 3;
    int lchk = lane & 7;
    char* Ac = (char*)As;
    char* Bc = (char*)Bs;

    f32x4 acc[2][4];
    #pragma unroll
    for (int i = 0; i < 2; ++i)
        #pragma unroll
        for (int j = 0; j < 4; ++j)
            acc[i][j] = (f32x4){0.f, 0.f, 0.f, 0.f};

    const int lane15 = lane & 15;
    const int kbyte = (lane >> 4) << 4;
    const int swa = (lane & 7) << 4;

    for (int kc = 0; kc < Kc; kc += 64) {
        // A: 64 rows; wave w stages rows w*16..w*16+15 (dest = wave base + lane*16)
        #pragma unroll
        for (int q = 0; q < 2; ++q) {
            int row = (w << 4) + (q << 3) + lr8;
            int sc = lchk ^ (row & 7);       // pre-swizzled source, linear LDS dest
            gl_lds16(amb + (size_t)row * L + kc + sc * 8, Ac + row * 128 + lchk * 16);
        }
        // B: 128 rows; wave w stages rows w*8+q*32.. (lane-linear)
        #pragma unroll
        for (int q = 0; q < 4; ++q) {
            int row = (w << 3) + (q << 5) + lr8;
            int sc = lchk ^ (row & 7);
            gl_lds16(yb + (size_t)row * L + kc + sc * 8, Bc + row * 128 + lchk * 16);
        }
        asm volatile("s_waitcnt vmcnt(0)" ::: "memory");
        __syncthreads();
        #pragma unroll
        for (int kk = 0; kk < 2; ++kk) {
            s16x8 af[2], bg[4];
            #pragma unroll
            for (int f = 0; f < 2; ++f) {
                int ar = wr + (f << 4) + lane15;
                af[f] = *(const s16x8*)(Ac + ar * 128 + (((kk << 6) + kbyte) ^ ((ar & 7) << 4)));
            }
            #pragma unroll
            for (int f = 0; f < 4; ++f) {
                int br = wc + (f << 4) + lane15;
                bg[f] = *(const s16x8*)(Bc + br * 128 + (((kk << 6) + kbyte) ^ swa));
            }
            #pragma unroll
            for (int fm = 0; fm < 2; ++fm)
                #pragma unroll
                for (int fn = 0; fn < 4; ++fn)
                    acc[fm][fn] = __builtin_amdgcn_mfma_f32_16x16x32_bf16(af[fm], bg[fn], acc[fm][fn], 0, 0, 0);
        }
        __syncthreads();
    }

    int col = lane15;
    int r0 = (lane >> 4) << 2;
    size_t bL = (size_t)b * L;
    #pragma unroll
    for (int fm = 0; fm < 2; ++fm) {
        #pragma unroll
        for (int j = 0; j < 4; ++j) {
            int rcmp = brow + wr + (fm << 4) + r0 + j;
            if (rcmp < Mc) {
                int gi = idxb[rcmp];
                float rsi = rs[bL + gi];
                float rfi = rself[bL + gi];
                const unsigned short* xrow = xb + (bL + gi) * (size_t)D;
                unsigned short* orow = aggh + (bL + gi) * (size_t)D;
                #pragma unroll
                for (int fn = 0; fn < 4; ++fn) {
                    int gd = bcol + wc + (fn << 4) + col;
                    float v = rsi * acc[fm][fn][j] + rfi * bf2f(xrow[gd]);
                    orow[gd] = cv_bf16(v);
                }
            }
        }
    }
}

// ---------------- K5: out = LN(x + relu(agg @ W^T + b) * D^-0.5)  (BM=32 x BN=512) ----------------
__global__ __launch_bounds__(256, 2) void k_linln(
    const unsigned short* __restrict__ aggh,
    const unsigned short* __restrict__ Wh,
    const float* __restrict__ bias,
    const unsigned short* __restrict__ xb,
    const float* __restrict__ lnw,
    const float* __restrict__ lnb,
    float* __restrict__ out)
{
    const int D = 512;
    __shared__ __align__(16) unsigned short As[32 * 64];    // 4KB
    __shared__ __align__(16) unsigned short Bs[512 * 64];   // 64KB
    __shared__ float psum[32][4], psq[32][4];

    int i0 = blockIdx.x << 5;
    int t = threadIdx.x;
    int lane = t & 63;
    int w = t >> 6;
    int wcol = w << 7;

    int srow = t >> 3;               // 0..31 (lane-linear dest)
    int chunk = t & 7;
    char* Ac = (char*)As;
    char* Bc = (char*)Bs;

    f32x4 acc[2][8];
    #pragma unroll
    for (int i = 0; i < 2; ++i)
        #pragma unroll
        for (int j = 0; j < 8; ++j)
            acc[i][j] = (f32x4){0.f, 0.f, 0.f, 0.f};

    const int lane15 = lane & 15;
    const int kbyte = (lane >> 4) << 4;
    const int swa = (lane & 7) << 4;

    for (int kc = 0; kc < D; kc += 64) {
        {   // A: 32 rows of aggh
            int sc = chunk ^ (srow & 7);
            gl_lds16(aggh + (size_t)(i0 + srow) * D + kc + sc * 8, Ac + srow * 128 + chunk * 16);
        }
        #pragma unroll
        for (int q = 0; q < 16; ++q) {   // B: all 512 rows of Wh
            int row = srow + (q << 5);
            int sc = chunk ^ (row & 7);
            gl_lds16(Wh + (size_t)row * D + kc + sc * 8, Bc + row * 128 + chunk * 16);
        }
        asm volatile("s_waitcnt vmcnt(0)" ::: "memory");
        __syncthreads();
        #pragma unroll
        for (int kk = 0; kk < 2; ++kk) {
            s16x8 af[2], bg[8];
            #pragma unroll
            for (int f = 0; f < 2; ++f) {
                int ar = (f << 4) + lane15;
                af[f] = *(const s16x8*)(Ac + ar * 128 + (((kk << 6) + kbyte) ^ ((ar & 7) << 4)));
            }
            #pragma unroll
            for (int f = 0; f < 8; ++f) {
                int br = wcol + (f << 4) + lane15;
                bg[f] = *(const s16x8*)(Bc + br * 128 + (((kk << 6) + kbyte) ^ swa));
            }
            #pragma unroll
            for (int fm = 0; fm < 2; ++fm)
                #pragma unroll
                for (int fn = 0; fn < 8; ++fn)
                    acc[fm][fn] = __builtin_amdgcn_mfma_f32_16x16x32_bf16(af[fm], bg[fn], acc[fm][fn], 0, 0, 0);
        }
        __syncthreads();
    }

    const float scale = 0.044194173824159216f;   // 512^-0.5
    float bi[8], lw[8], lb[8];
    #pragma unroll
    for (int fn = 0; fn < 8; ++fn) {
        int colg = wcol + (fn << 4) + lane15;
        bi[fn] = bias[colg];
        lw[fn] = lnw[colg];
        lb[fn] = lnb[colg];
    }
    int r0 = (lane >> 4) << 2;
    #pragma unroll
    for (int fm = 0; fm < 2; ++fm) {
        #pragma unroll
        for (int j = 0; j < 4; ++j) {
            int r = (fm << 4) + r0 + j;
            const unsigned short* xrow = xb + (size_t)(i0 + r) * D;
            float s = 0.f, q = 0.f;
            #pragma unroll
            for (int fn = 0; fn < 8; ++fn) {
                int colg = wcol + (fn << 4) + lane15;
                float v = fmaxf(acc[fm][fn][j] + bi[fn], 0.f) * scale + bf2f(xrow[colg]);
                acc[fm][fn][j] = v;
                s += v;
                q += v * v;
            }
            #pragma unroll
            for (int m = 1; m < 16; m <<= 1) {
                s += __shfl_xor(s, m);
                q += __shfl_xor(q, m);
            }
            if (lane15 == 0) { psum[r][w] = s; psq[r][w] = q; }
        }
    }
    __syncthreads();
    #pragma unroll
    for (int fm = 0; fm < 2; ++fm) {
        #pragma unroll
        for (int j = 0; j < 4; ++j) {
            int r = (fm << 4) + r0 + j;
            float s = psum[r][0] + psum[r][1] + psum[r][2] + psum[r][3];
            float q = psq[r][0] + psq[r][1] + psq[r][2] + psq[r][3];
            float mu = s * (1.f / 512.f);
            float var = q * (1.f / 512.f) - mu * mu;
            float rstd = rsqrtf(var + LN_EPS);
            float* orow = out + (size_t)(i0 + r) * D;
            #pragma unroll
            for (int fn = 0; fn < 8; ++fn) {
                int colg = wcol + (fn << 4) + lane15;
                orow[colg] = lw[fn] * (acc[fm][fn][j] - mu) * rstd + lb[fn];
            }
        }
    }
}

extern "C" void kernel_launch(void* const* d_in, const int* in_sizes, int n_in,
                              void* d_out, int out_size, void* d_ws, size_t ws_size,
                              hipStream_t stream) {
    const float* x    = (const float*)d_in[0];
    const float* adj  = (const float*)d_in[1];
    const int*   pm   = (const int*)d_in[2];
    const float* W    = (const float*)d_in[3];
    const float* bias = (const float*)d_in[4];
    const float* lnw  = (const float*)d_in[5];
    const float* lnb  = (const float*)d_in[6];
    const float* ew   = (const float*)d_in[7];

    int BL = in_sizes[2];                 // B*L = 16384
    int L  = in_sizes[1] / BL;            // 2048
    int B  = BL / L;                      // 8
    int D  = in_sizes[0] / BL;            // 512

    char* ws = (char*)d_ws;
    size_t off = 0;
    float* dis   = (float*)(ws + off); off += (size_t)BL * 4;
    float* rs    = (float*)(ws + off); off += (size_t)BL * 4;
    float* rself = (float*)(ws + off); off += (size_t)BL * 4;
    unsigned short* pos = (unsigned short*)(ws + off); off += (size_t)BL * 2;
    unsigned short* idx = (unsigned short*)(ws + off); off += (size_t)BL * 2;
    int* cnt = (int*)(ws + off); off += 64;
    unsigned short* amc  = (unsigned short*)(ws + off); off += (size_t)BL * L * 2;
    unsigned short* yc   = (unsigned short*)(ws + off); off += (size_t)BL * D * 2;
    unsigned short* Wh   = (unsigned short*)(ws + off); off += (size_t)D * D * 2;
    unsigned short* aggh = (unsigned short*)(ws + off); off += (size_t)BL * D * 2;
    unsigned short* xb   = (unsigned short*)(ws + off); off += (size_t)BL * D * 2;

    float* out = (float*)d_out;
    int nx = (BL * D) / (256 * 8);        // 4096 data blocks for k_xb

    k_scan<<<B, 256, 0, stream>>>(pm, pos, idx, cnt, L);
    k_deg<<<BL, 256, 0, stream>>>(adj, pm, ew, pos, cnt, dis, rs, rself, amc, L);
    k_xb<<<nx + (D * D) / (256 * 16), 256, 0, stream>>>(x, pm, ew, W, xb, aggh, Wh, nx);
    k_yt<<<dim3(L / 64, D / 64, B), 256, 0, stream>>>(x, dis, idx, cnt, yc, L, D);
    k_aggmm<<<B * (L / 64) * (D / 128), 256, 0, stream>>>(amc, yc, xb, rs, rself, idx, cnt, aggh, L, D);
    k_linln<<<BL / 32, 256, 0, stream>>>(aggh, Wh, bias, xb, lnw, lnb, out);
}

// Round 10
// 96.332 us; speedup vs baseline: 1.2953x; 1.1008x over previous
//
#include <hip/hip_runtime.h>

#define LN_EPS 1e-5f

typedef __attribute__((ext_vector_type(8))) short s16x8;
typedef __attribute__((ext_vector_type(4))) float f32x4;
typedef long long i64b;

__device__ inline unsigned int pk_bf16(float a, float b) {
    unsigned ua = __builtin_bit_cast(unsigned, a);
    unsigned ub = __builtin_bit_cast(unsigned, b);
    ua += 0x7fffu + ((ua >> 16) & 1u);
    ub += 0x7fffu + ((ub >> 16) & 1u);
    return (ua >> 16) | (ub & 0xffff0000u);
}
__device__ inline unsigned short cv_bf16(float a) {
    unsigned ua = __builtin_bit_cast(unsigned, a);
    ua += 0x7fffu + ((ua >> 16) & 1u);
    return (unsigned short)(ua >> 16);
}
__device__ inline float bf2f(unsigned short h) {
    unsigned u = ((unsigned)h) << 16;
    return __builtin_bit_cast(float, u);
}
__device__ inline unsigned pk2_fp8(float a, float b) {   // 2 fp8 e4m3 in bits[15:0]
    return (unsigned)__builtin_amdgcn_cvt_pk_fp8_f32(a, b, 0, false) & 0xffffu;
}
__device__ inline unsigned char cv_fp8(float a) {
    return (unsigned char)((unsigned)__builtin_amdgcn_cvt_pk_fp8_f32(a, 0.f, 0, false) & 0xffu);
}
__device__ inline void gl_lds16(const void* g, void* l) {
    __builtin_amdgcn_global_load_lds((const __attribute__((address_space(1))) void*)g,
                                     (__attribute__((address_space(3))) void*)l, 16, 0, 0);
}

// ---------------- K0: per-batch scan of valid mask -> pos, idx, cnt ----------------
__global__ __launch_bounds__(256) void k_scan(const int* __restrict__ pm,
                                              unsigned short* __restrict__ pos,
                                              unsigned short* __restrict__ idx,
                                              int* __restrict__ cnt, int L) {
    int b = blockIdx.x, t = threadIdx.x;
    const int* pmb = pm + (size_t)b * L;
    int j0 = t * 8;
    int v[8]; int s = 0;
    #pragma unroll
    for (int k = 0; k < 8; ++k) { v[k] = (pmb[j0 + k] == 0) ? 1 : 0; s += v[k]; }
    __shared__ int ps[256];
    ps[t] = s;
    __syncthreads();
    for (int off = 1; off < 256; off <<= 1) {
        int val = (t >= off) ? ps[t - off] : 0;
        __syncthreads();
        ps[t] += val;
        __syncthreads();
    }
    int base = ps[t] - s;   // exclusive prefix
    unsigned short* posb = pos + (size_t)b * L;
    unsigned short* idxb = idx + (size_t)b * L;
    #pragma unroll
    for (int k = 0; k < 8; ++k) {
        posb[j0 + k] = (unsigned short)base;
        if (v[k]) { idxb[base] = (unsigned short)(j0 + k); base++; }
    }
    if (t == 255) cnt[b] = ps[255];
}

// ---------------- K1: merged degree+amc(fp8)  |  xb/aggh-padded  |  W->Wh ----------------
__global__ __launch_bounds__(256) void k_degxb(const float* __restrict__ adj,
                                               const int* __restrict__ pm,
                                               const float* __restrict__ ew,
                                               const float* __restrict__ W,
                                               const unsigned short* __restrict__ pos,
                                               const int* __restrict__ cnt,
                                               float* __restrict__ dis_o,
                                               float* __restrict__ rs,
                                               float* __restrict__ rself,
                                               unsigned char* __restrict__ amc8,
                                               const float* __restrict__ x,
                                               unsigned short* __restrict__ xb,
                                               unsigned short* __restrict__ aggh,
                                               unsigned short* __restrict__ Wh,
                                               int L, int nd, int nx) {
    const int D = 512;
    int bid = blockIdx.x;
    int t = threadIdx.x;
    float e = ew[0];
    if (bid >= nd) {
        int sub = bid - nd;
        if (sub >= nx) {                // W -> bf16
            int i = ((sub - nx) * 256 + t) * 16;
            #pragma unroll
            for (int k = 0; k < 16; k += 4) {
                float4 v = *(const float4*)(W + i + k);
                uint2 o;
                o.x = pk_bf16(v.x, v.y);
                o.y = pk_bf16(v.z, v.w);
                *(uint2*)(Wh + i + k) = o;
            }
            return;
        }
        // xb = bf16(x); aggh = bf16(e*x) for padded rows
        int gid = sub * 256 + t;
        int row = gid >> 6;
        int co = (gid & 63) << 3;
        const float* xp = x + (size_t)row * D + co;
        float4 v0 = *(const float4*)(xp);
        float4 v1 = *(const float4*)(xp + 4);
        uint4 o;
        o.x = pk_bf16(v0.x, v0.y);
        o.y = pk_bf16(v0.z, v0.w);
        o.z = pk_bf16(v1.x, v1.y);
        o.w = pk_bf16(v1.z, v1.w);
        *(uint4*)(xb + (size_t)row * D + co) = o;
        if (pm[row] != 0) {
            uint4 oa;
            oa.x = pk_bf16(e * v0.x, e * v0.y);
            oa.y = pk_bf16(e * v0.z, e * v0.w);
            oa.z = pk_bf16(e * v1.x, e * v1.y);
            oa.w = pk_bf16(e * v1.z, e * v1.w);
            *(uint4*)(aggh + (size_t)row * D + co) = oa;
        }
        return;
    }
    // degree + compacted fp8 adjacency row
    int row = bid;
    int b = row / L;
    int i = row - b * L;
    const int* pmb = pm + (size_t)b * L;
    if (pmb[i] != 0) {                  // padded row: deg = 1
        if (t == 0) { dis_o[row] = 1.f; rs[row] = 0.f; rself[row] = e; }
        return;
    }
    __shared__ __align__(16) unsigned char ls8[2048 + 16];
    __shared__ float wsum[4];
    const float* arow = adj + (size_t)row * L;
    const unsigned short* posb = pos + (size_t)b * L;
    int rloc = posb[i];
    int cb = cnt[b];
    int kcap = (cb + 63) & ~63;

    for (int k = cb + t; k < kcap; k += 256) ls8[k] = 0;

    int j0 = t * 8;
    float4 a0 = *(const float4*)(arow + j0);
    float4 a1 = *(const float4*)(arow + j0 + 4);
    int4 p0 = *(const int4*)(pmb + j0);
    int4 p1 = *(const int4*)(pmb + j0 + 4);
    uint4 pv = *(const uint4*)(posb + j0);
    unsigned pc0 = pv.x & 0xffffu, pc1 = pv.x >> 16;
    unsigned pc2 = pv.y & 0xffffu, pc3 = pv.y >> 16;
    unsigned pc4 = pv.z & 0xffffu, pc5 = pv.z >> 16;
    unsigned pc6 = pv.w & 0xffffu, pc7 = pv.w >> 16;
    float m0 = p0.x == 0 ? a0.x : 0.f;
    float m1 = p0.y == 0 ? a0.y : 0.f;
    float m2 = p0.z == 0 ? a0.z : 0.f;
    float m3 = p0.w == 0 ? a0.w : 0.f;
    float m4 = p1.x == 0 ? a1.x : 0.f;
    float m5 = p1.y == 0 ? a1.y : 0.f;
    float m6 = p1.z == 0 ? a1.z : 0.f;
    float m7 = p1.w == 0 ? a1.w : 0.f;
    float s = ((m0 + m1) + (m2 + m3)) + ((m4 + m5) + (m6 + m7));
    if (p0.x == 0) ls8[pc0] = cv_fp8(m0);
    if (p0.y == 0) ls8[pc1] = cv_fp8(m1);
    if (p0.z == 0) ls8[pc2] = cv_fp8(m2);
    if (p0.w == 0) ls8[pc3] = cv_fp8(m3);
    if (p1.x == 0) ls8[pc4] = cv_fp8(m4);
    if (p1.y == 0) ls8[pc5] = cv_fp8(m5);
    if (p1.z == 0) ls8[pc6] = cv_fp8(m6);
    if (p1.w == 0) ls8[pc7] = cv_fp8(m7);

    #pragma unroll
    for (int off = 32; off; off >>= 1) s += __shfl_down(s, off);
    if ((t & 63) == 0) wsum[t >> 6] = s;
    __syncthreads();

    unsigned char* amrow = amc8 + ((size_t)b * L + rloc) * L;
    int j0b = t * 8;
    if (j0b < kcap) *(uint2*)(amrow + j0b) = *(const uint2*)(ls8 + j0b);

    if (t == 0) {
        float tot = wsum[0] + wsum[1] + wsum[2] + wsum[3];
        float d = rsqrtf(1.f + tot);
        dis_o[row]  = d;
        rs[row]     = e * d;
        rself[row]  = e * d * d;
    }
}

// ---------------- K3: compacted transpose: yc8[b, d, k] = fp8(dis[idx_k] * x[idx_k, d]) ----------------
__global__ __launch_bounds__(256) void k_yt(const float* __restrict__ x,
                                            const float* __restrict__ dis,
                                            const unsigned short* __restrict__ idx,
                                            const int* __restrict__ cnt,
                                            unsigned char* __restrict__ yc8,
                                            int L, int D) {
    int b = blockIdx.z;
    int kb = blockIdx.x << 6;
    int db = blockIdx.y << 6;
    int cb = cnt[b];
    if (kb >= cb) return;
    __shared__ float tile[64][65];
    int t = threadIdx.x;
    int kk = t >> 2, c4 = (t & 3) << 4;
    int kg = kb + kk;
    if (kg < cb) {
        int ol = idx[(size_t)b * L + kg];
        float dl = dis[(size_t)b * L + ol];
        const float* xp = x + ((size_t)b * L + ol) * D + db + c4;
        #pragma unroll
        for (int k = 0; k < 16; k += 4) {
            float4 v = *(const float4*)(xp + k);
            tile[kk][c4 + k + 0] = v.x * dl;
            tile[kk][c4 + k + 1] = v.y * dl;
            tile[kk][c4 + k + 2] = v.z * dl;
            tile[kk][c4 + k + 3] = v.w * dl;
        }
    } else {
        #pragma unroll
        for (int k = 0; k < 16; ++k) tile[kk][c4 + k] = 0.f;
    }
    __syncthreads();
    int dr = t >> 2, k0 = (t & 3) << 4;
    unsigned char* op = yc8 + ((size_t)b * D + db + dr) * L + kb + k0;
    uint4 o;
    o.x = pk2_fp8(tile[k0 + 0][dr],  tile[k0 + 1][dr])  | (pk2_fp8(tile[k0 + 2][dr],  tile[k0 + 3][dr])  << 16);
    o.y = pk2_fp8(tile[k0 + 4][dr],  tile[k0 + 5][dr])  | (pk2_fp8(tile[k0 + 6][dr],  tile[k0 + 7][dr])  << 16);
    o.z = pk2_fp8(tile[k0 + 8][dr],  tile[k0 + 9][dr])  | (pk2_fp8(tile[k0 + 10][dr], tile[k0 + 11][dr]) << 16);
    o.w = pk2_fp8(tile[k0 + 12][dr], tile[k0 + 13][dr]) | (pk2_fp8(tile[k0 + 14][dr], tile[k0 + 15][dr]) << 16);
    *(uint4*)(op) = o;
}

// ---------------- K4: compacted fp8 GEMM: agg[idx_i] = rs_i*(amc8 @ yc8) + rself_i*x ----------------
// mfma_f32_16x16x32_fp8_fp8; BM=64, BN=128, BK=64; 4 waves of 32x64; 12KB LDS.
__global__ __launch_bounds__(256) void k_aggmm(
    const unsigned char* __restrict__ amc8,
    const unsigned char* __restrict__ yc8,
    const unsigned short* __restrict__ xb,
    const float* __restrict__ rs,
    const float* __restrict__ rself,
    const unsigned short* __restrict__ idx,
    const int* __restrict__ cnt,
    unsigned short* __restrict__ aggh,
    int L, int D)
{
    __shared__ __align__(16) unsigned char As[64 * 64];     // 4KB
    __shared__ __align__(16) unsigned char Bs[128 * 64];    // 8KB
    int bid = blockIdx.x;
    int wid = (bid & 7) * 128 + (bid >> 3);  // 1024 = 8*128, bijective; one batch per XCD
    int b   = wid >> 7;
    int t6  = wid & 127;
    int brow = (t6 >> 2) << 6;               // compacted row base
    int bcol = (t6 & 3) << 7;

    int Mc = cnt[b];
    if (brow >= Mc) return;                  // uniform early-exit
    int Kc = (Mc + 63) & ~63;

    int t = threadIdx.x;
    int lane = t & 63;
    int w = t >> 6;
    int wr = ((w >> 1) & 1) << 5;            // 0 or 32
    int wc = (w & 1) << 6;                   // 0 or 64

    const unsigned char* amb = amc8 + ((size_t)b * L + brow) * L;
    const unsigned char* yb  = yc8 + ((size_t)b * D + bcol) * L;
    const unsigned short* idxb = idx + (size_t)b * L;

    int r4 = t >> 2;                         // 0..63
    int c4 = t & 3;

    f32x4 acc[2][4];
    #pragma unroll
    for (int i = 0; i < 2; ++i)
        #pragma unroll
        for (int j = 0; j < 4; ++j)
            acc[i][j] = (f32x4){0.f, 0.f, 0.f, 0.f};

    const int lane15 = lane & 15;
    const int k8 = (lane >> 4) << 3;         // 8B k-chunk per lane

    for (int kc = 0; kc < Kc; kc += 64) {
        {   // A: 64 rows x 64B; one 16B issue per thread (dest = t*16, lane-linear)
            int sc = c4 ^ (r4 & 3);          // pre-swizzled source, linear LDS dest
            gl_lds16(amb + (size_t)r4 * L + kc + sc * 16, As + r4 * 64 + c4 * 16);
        }
        #pragma unroll
        for (int q = 0; q < 2; ++q) {        // B: 128 rows x 64B; 2 issues
            int row = (q << 6) + r4;
            int sc = c4 ^ (row & 3);
            gl_lds16(yb + (size_t)row * L + kc + sc * 16, Bs + row * 64 + c4 * 16);
        }
        asm volatile("s_waitcnt vmcnt(0)" ::: "memory");
        __syncthreads();
        #pragma unroll
        for (int kk = 0; kk < 2; ++kk) {
            i64b af[2], bg[4];
            #pragma unroll
            for (int f = 0; f < 2; ++f) {
                int ar = wr + (f << 4) + lane15;
                af[f] = *(const i64b*)(As + ar * 64 + (((kk << 5) + k8) ^ ((ar & 3) << 4)));
            }
            #pragma unroll
            for (int f = 0; f < 4; ++f) {
                int br = wc + (f << 4) + lane15;
                bg[f] = *(const i64b*)(Bs + br * 64 + (((kk << 5) + k8) ^ ((br & 3) << 4)));
            }
            #pragma unroll
            for (int fm = 0; fm < 2; ++fm)
                #pragma unroll
                for (int fn = 0; fn < 4; ++fn)
                    acc[fm][fn] = __builtin_amdgcn_mfma_f32_16x16x32_fp8_fp8(af[fm], bg[fn], acc[fm][fn], 0, 0, 0);
        }
        __syncthreads();
    }

    int col = lane15;
    int r0 = (lane >> 4) << 2;
    size_t bL = (size_t)b * L;
    #pragma unroll
    for (int fm = 0; fm < 2; ++fm) {
        #pragma unroll
        for (int j = 0; j < 4; ++j) {
            int rcmp = brow + wr + (fm << 4) + r0 + j;
            if (rcmp < Mc) {
                int gi = idxb[rcmp];
                float rsi = rs[bL + gi];
                float rfi = rself[bL + gi];
                const unsigned short* xrow = xb + (bL + gi) * (size_t)D;
                unsigned short* orow = aggh + (bL + gi) * (size_t)D;
                #pragma unroll
                for (int fn = 0; fn < 4; ++fn) {
                    int gd = bcol + wc + (fn << 4) + col;
                    float v = rsi * acc[fm][fn][j] + rfi * bf2f(xrow[gd]);
                    orow[gd] = cv_bf16(v);
                }
            }
        }
    }
}

// ---------------- K5: out = LN(x + relu(agg @ W^T + b) * D^-0.5)  (BM=32 x BN=512, bf16) ----------------
__global__ __launch_bounds__(256, 2) void k_linln(
    const unsigned short* __restrict__ aggh,
    const unsigned short* __restrict__ Wh,
    const float* __restrict__ bias,
    const unsigned short* __restrict__ xb,
    const float* __restrict__ lnw,
    const float* __restrict__ lnb,
    float* __restrict__ out)
{
    const int D = 512;
    __shared__ __align__(16) unsigned short As[32 * 64];    // 4KB
    __shared__ __align__(16) unsigned short Bs[512 * 64];   // 64KB
    __shared__ float psum[32][4], psq[32][4];

    int i0 = blockIdx.x << 5;
    int t = threadIdx.x;
    int lane = t & 63;
    int w = t >> 6;
    int wcol = w << 7;

    int srow = t >> 3;               // 0..31 (lane-linear dest)
    int chunk = t & 7;
    char* Ac = (char*)As;
    char* Bc = (char*)Bs;

    f32x4 acc[2][8];
    #pragma unroll
    for (int i = 0; i < 2; ++i)
        #pragma unroll
        for (int j = 0; j < 8; ++j)
            acc[i][j] = (f32x4){0.f, 0.f, 0.f, 0.f};

    const int lane15 = lane & 15;
    const int kbyte = (lane >> 4) << 4;
    const int swa = (lane & 7) << 4;

    for (int kc = 0; kc < D; kc += 64) {
        {   // A: 32 rows of aggh
            int sc = chunk ^ (srow & 7);
            gl_lds16(aggh + (size_t)(i0 + srow) * D + kc + sc * 8, Ac + srow * 128 + chunk * 16);
        }
        #pragma unroll
        for (int q = 0; q < 16; ++q) {   // B: all 512 rows of Wh
            int row = srow + (q << 5);
            int sc = chunk ^ (row & 7);
            gl_lds16(Wh + (size_t)row * D + kc + sc * 8, Bc + row * 128 + chunk * 16);
        }
        asm volatile("s_waitcnt vmcnt(0)" ::: "memory");
        __syncthreads();
        #pragma unroll
        for (int kk = 0; kk < 2; ++kk) {
            s16x8 af[2], bg[8];
            #pragma unroll
            for (int f = 0; f < 2; ++f) {
                int ar = (f << 4) + lane15;
                af[f] = *(const s16x8*)(Ac + ar * 128 + (((kk << 6) + kbyte) ^ ((ar & 7) << 4)));
            }
            #pragma unroll
            for (int f = 0; f < 8; ++f) {
                int br = wcol + (f << 4) + lane15;
                bg[f] = *(const s16x8*)(Bc + br * 128 + (((kk << 6) + kbyte) ^ swa));
            }
            #pragma unroll
            for (int fm = 0; fm < 2; ++fm)
                #pragma unroll
                for (int fn = 0; fn < 8; ++fn)
                    acc[fm][fn] = __builtin_amdgcn_mfma_f32_16x16x32_bf16(af[fm], bg[fn], acc[fm][fn], 0, 0, 0);
        }
        __syncthreads();
    }

    const float scale = 0.044194173824159216f;   // 512^-0.5
    float bi[8], lw[8], lb[8];
    #pragma unroll
    for (int fn = 0; fn < 8; ++fn) {
        int colg = wcol + (fn << 4) + lane15;
        bi[fn] = bias[colg];
        lw[fn] = lnw[colg];
        lb[fn] = lnb[colg];
    }
    int r0 = (lane >> 4) << 2;
    #pragma unroll
    for (int fm = 0; fm < 2; ++fm) {
        #pragma unroll
        for (int j = 0; j < 4; ++j) {
            int r = (fm << 4) + r0 + j;
            const unsigned short* xrow = xb + (size_t)(i0 + r) * D;
            float s = 0.f, q = 0.f;
            #pragma unroll
            for (int fn = 0; fn < 8; ++fn) {
                int colg = wcol + (fn << 4) + lane15;
                float v = fmaxf(acc[fm][fn][j] + bi[fn], 0.f) * scale + bf2f(xrow[colg]);
                acc[fm][fn][j] = v;
                s += v;
                q += v * v;
            }
            #pragma unroll
            for (int m = 1; m < 16; m <<= 1) {
                s += __shfl_xor(s, m);
                q += __shfl_xor(q, m);
            }
            if (lane15 == 0) { psum[r][w] = s; psq[r][w] = q; }
        }
    }
    __syncthreads();
    #pragma unroll
    for (int fm = 0; fm < 2; ++fm) {
        #pragma unroll
        for (int j = 0; j < 4; ++j) {
            int r = (fm << 4) + r0 + j;
            float s = psum[r][0] + psum[r][1] + psum[r][2] + psum[r][3];
            float q = psq[r][0] + psq[r][1] + psq[r][2] + psq[r][3];
            float mu = s * (1.f / 512.f);
            float var = q * (1.f / 512.f) - mu * mu;
            float rstd = rsqrtf(var + LN_EPS);
            float* orow = out + (size_t)(i0 + r) * D;
            #pragma unroll
            for (int fn = 0; fn < 8; ++fn) {
                int colg = wcol + (fn << 4) + lane15;
                orow[colg] = lw[fn] * (acc[fm][fn][j] - mu) * rstd + lb[fn];
            }
        }
    }
}

extern "C" void kernel_launch(void* const* d_in, const int* in_sizes, int n_in,
                              void* d_out, int out_size, void* d_ws, size_t ws_size,
                              hipStream_t stream) {
    const float* x    = (const float*)d_in[0];
    const float* adj  = (const float*)d_in[1];
    const int*   pm   = (const int*)d_in[2];
    const float* W    = (const float*)d_in[3];
    const float* bias = (const float*)d_in[4];
    const float* lnw  = (const float*)d_in[5];
    const float* lnb  = (const float*)d_in[6];
    const float* ew   = (const float*)d_in[7];

    int BL = in_sizes[2];                 // B*L = 16384
    int L  = in_sizes[1] / BL;            // 2048
    int B  = BL / L;                      // 8
    int D  = in_sizes[0] / BL;            // 512

    char* ws = (char*)d_ws;
    size_t off = 0;
    float* dis   = (float*)(ws + off); off += (size_t)BL * 4;
    float* rs    = (float*)(ws + off); off += (size_t)BL * 4;
    float* rself = (float*)(ws + off); off += (size_t)BL * 4;
    unsigned short* pos = (unsigned short*)(ws + off); off += (size_t)BL * 2;
    unsigned short* idx = (unsigned short*)(ws + off); off += (size_t)BL * 2;
    int* cnt = (int*)(ws + off); off += 64;
    unsigned char* amc8 = (unsigned char*)(ws + off); off += (size_t)BL * L;
    unsigned char* yc8  = (unsigned char*)(ws + off); off += (size_t)BL * D;
    unsigned short* Wh   = (unsigned short*)(ws + off); off += (size_t)D * D * 2;
    unsigned short* aggh = (unsigned short*)(ws + off); off += (size_t)BL * D * 2;
    unsigned short* xb   = (unsigned short*)(ws + off); off += (size_t)BL * D * 2;

    float* out = (float*)d_out;
    int nx = (BL * D) / (256 * 8);        // 4096 xb data blocks
    int nw = (D * D) / (256 * 16);        // 64 W-convert blocks

    k_scan<<<B, 256, 0, stream>>>(pm, pos, idx, cnt, L);
    k_degxb<<<BL + nx + nw, 256, 0, stream>>>(adj, pm, ew, W, pos, cnt,
                                              dis, rs, rself, amc8, x, xb, aggh, Wh, L, BL, nx);
    k_yt<<<dim3(L / 64, D / 64, B), 256, 0, stream>>>(x, dis, idx, cnt, yc8, L, D);
    k_aggmm<<<B * (L / 64) * (D / 128), 256, 0, stream>>>(amc8, yc8, xb, rs, rself, idx, cnt, aggh, L, D);
    k_linln<<<BL / 32, 256, 0, stream>>>(aggh, Wh, bias, xb, lnw, lnb, out);
}

// Round 11
// 84.394 us; speedup vs baseline: 1.4785x; 1.1415x over previous
//
#include <hip/hip_runtime.h>

#define LN_EPS 1e-5f

typedef __attribute__((ext_vector_type(8))) short s16x8;
typedef __attribute__((ext_vector_type(4))) float f32x4;
typedef long long i64b;

__device__ inline unsigned int pk_bf16(float a, float b) {
    unsigned ua = __builtin_bit_cast(unsigned, a);
    unsigned ub = __builtin_bit_cast(unsigned, b);
    ua += 0x7fffu + ((ua >> 16) & 1u);
    ub += 0x7fffu + ((ub >> 16) & 1u);
    return (ua >> 16) | (ub & 0xffff0000u);
}
__device__ inline unsigned short cv_bf16(float a) {
    unsigned ua = __builtin_bit_cast(unsigned, a);
    ua += 0x7fffu + ((ua >> 16) & 1u);
    return (unsigned short)(ua >> 16);
}
__device__ inline float bf2f(unsigned short h) {
    unsigned u = ((unsigned)h) << 16;
    return __builtin_bit_cast(float, u);
}
__device__ inline unsigned pk2_fp8(float a, float b) {   // 2 fp8 e4m3 in bits[15:0]
    return (unsigned)__builtin_amdgcn_cvt_pk_fp8_f32(a, b, 0, false) & 0xffffu;
}
__device__ inline unsigned char cv_fp8(float a) {
    return (unsigned char)((unsigned)__builtin_amdgcn_cvt_pk_fp8_f32(a, 0.f, 0, false) & 0xffu);
}
__device__ inline void gl_lds16(const void* g, void* l) {
    __builtin_amdgcn_global_load_lds((const __attribute__((address_space(1))) void*)g,
                                     (__attribute__((address_space(3))) void*)l, 16, 0, 0);
}

// ---------------- K0: per-batch scan of valid mask -> pos, idx, cnt ----------------
__global__ __launch_bounds__(256) void k_scan(const int* __restrict__ pm,
                                              unsigned short* __restrict__ pos,
                                              unsigned short* __restrict__ idx,
                                              int* __restrict__ cnt, int L) {
    int b = blockIdx.x, t = threadIdx.x;
    const int* pmb = pm + (size_t)b * L;
    int j0 = t * 8;
    int v[8]; int s = 0;
    #pragma unroll
    for (int k = 0; k < 8; ++k) { v[k] = (pmb[j0 + k] == 0) ? 1 : 0; s += v[k]; }
    __shared__ int ps[256];
    ps[t] = s;
    __syncthreads();
    for (int off = 1; off < 256; off <<= 1) {
        int val = (t >= off) ? ps[t - off] : 0;
        __syncthreads();
        ps[t] += val;
        __syncthreads();
    }
    int base = ps[t] - s;   // exclusive prefix
    unsigned short* posb = pos + (size_t)b * L;
    unsigned short* idxb = idx + (size_t)b * L;
    #pragma unroll
    for (int k = 0; k < 8; ++k) {
        posb[j0 + k] = (unsigned short)base;
        if (v[k]) { idxb[base] = (unsigned short)(j0 + k); base++; }
    }
    if (t == 255) cnt[b] = ps[255];
}

// ---------------- K1: merged degree+amc(fp8) | xb bf16 + agg8-padded | W->W8 ----------------
__global__ __launch_bounds__(256) void k_degxb(const float* __restrict__ adj,
                                               const int* __restrict__ pm,
                                               const float* __restrict__ ew,
                                               const float* __restrict__ W,
                                               const unsigned short* __restrict__ pos,
                                               const int* __restrict__ cnt,
                                               float* __restrict__ dis_o,
                                               float* __restrict__ rs,
                                               float* __restrict__ rself,
                                               unsigned char* __restrict__ amc8,
                                               const float* __restrict__ x,
                                               unsigned short* __restrict__ xb,
                                               unsigned char* __restrict__ agg8,
                                               unsigned char* __restrict__ W8,
                                               int L, int nd, int nx) {
    const int D = 512;
    int bid = blockIdx.x;
    int t = threadIdx.x;
    float e = ew[0];
    if (bid >= nd) {
        int sub = bid - nd;
        if (sub >= nx) {                // W -> fp8 (64 blocks x 256 thr x 16 elems)
            int i = ((sub - nx) * 256 + t) * 16;
            uint4 o;
            float4 v0 = *(const float4*)(W + i);
            float4 v1 = *(const float4*)(W + i + 4);
            float4 v2 = *(const float4*)(W + i + 8);
            float4 v3 = *(const float4*)(W + i + 12);
            o.x = pk2_fp8(v0.x, v0.y) | (pk2_fp8(v0.z, v0.w) << 16);
            o.y = pk2_fp8(v1.x, v1.y) | (pk2_fp8(v1.z, v1.w) << 16);
            o.z = pk2_fp8(v2.x, v2.y) | (pk2_fp8(v2.z, v2.w) << 16);
            o.w = pk2_fp8(v3.x, v3.y) | (pk2_fp8(v3.z, v3.w) << 16);
            *(uint4*)(W8 + i) = o;
            return;
        }
        // xb = bf16(x); agg8 = fp8(e*x) for padded rows
        int gid = sub * 256 + t;
        int row = gid >> 6;
        int co = (gid & 63) << 3;
        const float* xp = x + (size_t)row * D + co;
        float4 v0 = *(const float4*)(xp);
        float4 v1 = *(const float4*)(xp + 4);
        uint4 o;
        o.x = pk_bf16(v0.x, v0.y);
        o.y = pk_bf16(v0.z, v0.w);
        o.z = pk_bf16(v1.x, v1.y);
        o.w = pk_bf16(v1.z, v1.w);
        *(uint4*)(xb + (size_t)row * D + co) = o;
        if (pm[row] != 0) {
            uint2 oa;
            oa.x = pk2_fp8(e * v0.x, e * v0.y) | (pk2_fp8(e * v0.z, e * v0.w) << 16);
            oa.y = pk2_fp8(e * v1.x, e * v1.y) | (pk2_fp8(e * v1.z, e * v1.w) << 16);
            *(uint2*)(agg8 + (size_t)row * D + co) = oa;
        }
        return;
    }
    // degree + compacted fp8 adjacency row
    int row = bid;
    int b = row / L;
    int i = row - b * L;
    const int* pmb = pm + (size_t)b * L;
    if (pmb[i] != 0) {                  // padded row: deg = 1
        if (t == 0) { dis_o[row] = 1.f; rs[row] = 0.f; rself[row] = e; }
        return;
    }
    __shared__ __align__(16) unsigned char ls8[2048 + 16];
    __shared__ float wsum[4];
    const float* arow = adj + (size_t)row * L;
    const unsigned short* posb = pos + (size_t)b * L;
    int rloc = posb[i];
    int cb = cnt[b];
    int kcap = (cb + 63) & ~63;

    for (int k = cb + t; k < kcap; k += 256) ls8[k] = 0;

    int j0 = t * 8;
    float4 a0 = *(const float4*)(arow + j0);
    float4 a1 = *(const float4*)(arow + j0 + 4);
    int4 p0 = *(const int4*)(pmb + j0);
    int4 p1 = *(const int4*)(pmb + j0 + 4);
    uint4 pv = *(const uint4*)(posb + j0);
    unsigned pc0 = pv.x & 0xffffu, pc1 = pv.x >> 16;
    unsigned pc2 = pv.y & 0xffffu, pc3 = pv.y >> 16;
    unsigned pc4 = pv.z & 0xffffu, pc5 = pv.z >> 16;
    unsigned pc6 = pv.w & 0xffffu, pc7 = pv.w >> 16;
    float m0 = p0.x == 0 ? a0.x : 0.f;
    float m1 = p0.y == 0 ? a0.y : 0.f;
    float m2 = p0.z == 0 ? a0.z : 0.f;
    float m3 = p0.w == 0 ? a0.w : 0.f;
    float m4 = p1.x == 0 ? a1.x : 0.f;
    float m5 = p1.y == 0 ? a1.y : 0.f;
    float m6 = p1.z == 0 ? a1.z : 0.f;
    float m7 = p1.w == 0 ? a1.w : 0.f;
    float s = ((m0 + m1) + (m2 + m3)) + ((m4 + m5) + (m6 + m7));
    if (p0.x == 0) ls8[pc0] = cv_fp8(m0);
    if (p0.y == 0) ls8[pc1] = cv_fp8(m1);
    if (p0.z == 0) ls8[pc2] = cv_fp8(m2);
    if (p0.w == 0) ls8[pc3] = cv_fp8(m3);
    if (p1.x == 0) ls8[pc4] = cv_fp8(m4);
    if (p1.y == 0) ls8[pc5] = cv_fp8(m5);
    if (p1.z == 0) ls8[pc6] = cv_fp8(m6);
    if (p1.w == 0) ls8[pc7] = cv_fp8(m7);

    #pragma unroll
    for (int off = 32; off; off >>= 1) s += __shfl_down(s, off);
    if ((t & 63) == 0) wsum[t >> 6] = s;
    __syncthreads();

    unsigned char* amrow = amc8 + ((size_t)b * L + rloc) * L;
    int j0b = t * 8;
    if (j0b < kcap) *(uint2*)(amrow + j0b) = *(const uint2*)(ls8 + j0b);

    if (t == 0) {
        float tot = wsum[0] + wsum[1] + wsum[2] + wsum[3];
        float d = rsqrtf(1.f + tot);
        dis_o[row]  = d;
        rs[row]     = e * d;
        rself[row]  = e * d * d;
    }
}

// ---------------- K3: compacted transpose: yc8[b,d,k] = fp8(dis[idx_k] * xb[idx_k, d]) ----------------
__global__ __launch_bounds__(256) void k_yt(const unsigned short* __restrict__ xb,
                                            const float* __restrict__ dis,
                                            const unsigned short* __restrict__ idx,
                                            const int* __restrict__ cnt,
                                            unsigned char* __restrict__ yc8,
                                            int L, int D) {
    int b = blockIdx.z;
    int kb = blockIdx.x << 6;
    int db = blockIdx.y << 6;
    int cb = cnt[b];
    if (kb >= cb) return;
    __shared__ float tile[64][65];
    int t = threadIdx.x;
    int kk = t >> 2, c4 = (t & 3) << 4;
    int kg = kb + kk;
    if (kg < cb) {
        int ol = idx[(size_t)b * L + kg];
        float dl = dis[(size_t)b * L + ol];
        const unsigned short* xp = xb + ((size_t)b * L + ol) * D + db + c4;
        uint4 h0 = *(const uint4*)(xp);
        uint4 h1 = *(const uint4*)(xp + 8);
        unsigned hv[8] = {h0.x, h0.y, h0.z, h0.w, h1.x, h1.y, h1.z, h1.w};
        #pragma unroll
        for (int k = 0; k < 8; ++k) {
            tile[kk][c4 + 2 * k + 0] = bf2f((unsigned short)(hv[k] & 0xffffu)) * dl;
            tile[kk][c4 + 2 * k + 1] = bf2f((unsigned short)(hv[k] >> 16)) * dl;
        }
    } else {
        #pragma unroll
        for (int k = 0; k < 16; ++k) tile[kk][c4 + k] = 0.f;
    }
    __syncthreads();
    int dr = t >> 2, k0 = (t & 3) << 4;
    unsigned char* op = yc8 + ((size_t)b * D + db + dr) * L + kb + k0;
    uint4 o;
    o.x = pk2_fp8(tile[k0 + 0][dr],  tile[k0 + 1][dr])  | (pk2_fp8(tile[k0 + 2][dr],  tile[k0 + 3][dr])  << 16);
    o.y = pk2_fp8(tile[k0 + 4][dr],  tile[k0 + 5][dr])  | (pk2_fp8(tile[k0 + 6][dr],  tile[k0 + 7][dr])  << 16);
    o.z = pk2_fp8(tile[k0 + 8][dr],  tile[k0 + 9][dr])  | (pk2_fp8(tile[k0 + 10][dr], tile[k0 + 11][dr]) << 16);
    o.w = pk2_fp8(tile[k0 + 12][dr], tile[k0 + 13][dr]) | (pk2_fp8(tile[k0 + 14][dr], tile[k0 + 15][dr]) << 16);
    *(uint4*)(op) = o;
}

// ---------------- K4: compacted fp8 GEMM: agg8[idx_i] = fp8(rs_i*(amc8 @ yc8) + rself_i*x) ----------------
__global__ __launch_bounds__(256) void k_aggmm(
    const unsigned char* __restrict__ amc8,
    const unsigned char* __restrict__ yc8,
    const unsigned short* __restrict__ xb,
    const float* __restrict__ rs,
    const float* __restrict__ rself,
    const unsigned short* __restrict__ idx,
    const int* __restrict__ cnt,
    unsigned char* __restrict__ agg8,
    int L, int D)
{
    __shared__ __align__(16) unsigned char As[64 * 64];     // 4KB
    __shared__ __align__(16) unsigned char Bs[128 * 64];    // 8KB
    int bid = blockIdx.x;
    int wid = (bid & 7) * 128 + (bid >> 3);  // 1024 = 8*128, bijective; one batch per XCD
    int b   = wid >> 7;
    int t6  = wid & 127;
    int brow = (t6 >> 2) << 6;               // compacted row base
    int bcol = (t6 & 3) << 7;

    int Mc = cnt[b];
    if (brow >= Mc) return;                  // uniform early-exit
    int Kc = (Mc + 63) & ~63;

    int t = threadIdx.x;
    int lane = t & 63;
    int w = t >> 6;
    int wr = ((w >> 1) & 1) << 5;            // 0 or 32
    int wc = (w & 1) << 6;                   // 0 or 64

    const unsigned char* amb = amc8 + ((size_t)b * L + brow) * L;
    const unsigned char* yb  = yc8 + ((size_t)b * D + bcol) * L;
    const unsigned short* idxb = idx + (size_t)b * L;

    int r4 = t >> 2;                         // 0..63
    int c4 = t & 3;

    f32x4 acc[2][4];
    #pragma unroll
    for (int i = 0; i < 2; ++i)
        #pragma unroll
        for (int j = 0; j < 4; ++j)
            acc[i][j] = (f32x4){0.f, 0.f, 0.f, 0.f};

    const int lane15 = lane & 15;
    const int k8 = (lane >> 4) << 3;         // 8B k-chunk per lane

    for (int kc = 0; kc < Kc; kc += 64) {
        {   // A: 64 rows x 64B; one 16B issue per thread (dest = t*16, lane-linear)
            int sc = c4 ^ (r4 & 3);          // pre-swizzled source, linear LDS dest
            gl_lds16(amb + (size_t)r4 * L + kc + sc * 16, As + r4 * 64 + c4 * 16);
        }
        #pragma unroll
        for (int q = 0; q < 2; ++q) {        // B: 128 rows x 64B; 2 issues
            int row = (q << 6) + r4;
            int sc = c4 ^ (row & 3);
            gl_lds16(yb + (size_t)row * L + kc + sc * 16, Bs + row * 64 + c4 * 16);
        }
        asm volatile("s_waitcnt vmcnt(0)" ::: "memory");
        __syncthreads();
        #pragma unroll
        for (int kk = 0; kk < 2; ++kk) {
            i64b af[2], bg[4];
            #pragma unroll
            for (int f = 0; f < 2; ++f) {
                int ar = wr + (f << 4) + lane15;
                af[f] = *(const i64b*)(As + ar * 64 + (((kk << 5) + k8) ^ ((ar & 3) << 4)));
            }
            #pragma unroll
            for (int f = 0; f < 4; ++f) {
                int br = wc + (f << 4) + lane15;
                bg[f] = *(const i64b*)(Bs + br * 64 + (((kk << 5) + k8) ^ ((br & 3) << 4)));
            }
            #pragma unroll
            for (int fm = 0; fm < 2; ++fm)
                #pragma unroll
                for (int fn = 0; fn < 4; ++fn)
                    acc[fm][fn] = __builtin_amdgcn_mfma_f32_16x16x32_fp8_fp8(af[fm], bg[fn], acc[fm][fn], 0, 0, 0);
        }
        __syncthreads();
    }

    int col = lane15;
    int r0 = (lane >> 4) << 2;
    size_t bL = (size_t)b * L;
    #pragma unroll
    for (int fm = 0; fm < 2; ++fm) {
        #pragma unroll
        for (int j = 0; j < 4; ++j) {
            int rcmp = brow + wr + (fm << 4) + r0 + j;
            if (rcmp < Mc) {
                int gi = idxb[rcmp];
                float rsi = rs[bL + gi];
                float rfi = rself[bL + gi];
                const unsigned short* xrow = xb + (bL + gi) * (size_t)D;
                unsigned char* orow = agg8 + (bL + gi) * (size_t)D;
                #pragma unroll
                for (int fn = 0; fn < 4; ++fn) {
                    int gd = bcol + wc + (fn << 4) + col;
                    float v = rsi * acc[fm][fn][j] + rfi * bf2f(xrow[gd]);
                    orow[gd] = cv_fp8(v);
                }
            }
        }
    }
}

// ---------------- K5: out = LN(x + relu(agg8 @ W8^T + b) * D^-0.5)  (fp8 MFMA, BM=32 x BN=512) ----------------
__global__ __launch_bounds__(256) void k_linln(
    const unsigned char* __restrict__ agg8,
    const unsigned char* __restrict__ W8,
    const float* __restrict__ bias,
    const unsigned short* __restrict__ xb,
    const float* __restrict__ lnw,
    const float* __restrict__ lnb,
    float* __restrict__ out)
{
    const int D = 512;
    __shared__ __align__(16) unsigned char As[32 * 64];     // 2KB
    __shared__ __align__(16) unsigned char Bs[512 * 64];    // 32KB
    __shared__ float psum[32][4], psq[32][4];

    int i0 = blockIdx.x << 5;
    int t = threadIdx.x;
    int lane = t & 63;
    int w = t >> 6;
    int wcol = w << 7;

    int r4 = t >> 2;                 // 0..63
    int c4 = t & 3;

    f32x4 acc[2][8];
    #pragma unroll
    for (int i = 0; i < 2; ++i)
        #pragma unroll
        for (int j = 0; j < 8; ++j)
            acc[i][j] = (f32x4){0.f, 0.f, 0.f, 0.f};

    const int lane15 = lane & 15;
    const int k8 = (lane >> 4) << 3;

    for (int kc = 0; kc < D; kc += 64) {
        if (t < 128) {               // A: 32 rows x 64B; waves 0-1 (dest = t*16, lane-linear)
            int row = t >> 2;        // 0..31
            int sc = c4 ^ (row & 3);
            gl_lds16(agg8 + (size_t)(i0 + row) * D + kc + sc * 16, As + t * 16);
        }
        #pragma unroll
        for (int q = 0; q < 8; ++q) {    // B: 512 rows x 64B; 8 issues (dest lane-linear)
            int row = (q << 6) + r4;
            int sc = c4 ^ (row & 3);
            gl_lds16(W8 + (size_t)row * D + kc + sc * 16, Bs + row * 64 + c4 * 16);
        }
        asm volatile("s_waitcnt vmcnt(0)" ::: "memory");
        __syncthreads();
        #pragma unroll
        for (int kk = 0; kk < 2; ++kk) {
            i64b af[2], bg[8];
            #pragma unroll
            for (int f = 0; f < 2; ++f) {
                int ar = (f << 4) + lane15;
                af[f] = *(const i64b*)(As + ar * 64 + (((kk << 5) + k8) ^ ((ar & 3) << 4)));
            }
            #pragma unroll
            for (int f = 0; f < 8; ++f) {
                int br = wcol + (f << 4) + lane15;
                bg[f] = *(const i64b*)(Bs + br * 64 + (((kk << 5) + k8) ^ ((br & 3) << 4)));
            }
            #pragma unroll
            for (int fm = 0; fm < 2; ++fm)
                #pragma unroll
                for (int fn = 0; fn < 8; ++fn)
                    acc[fm][fn] = __builtin_amdgcn_mfma_f32_16x16x32_fp8_fp8(af[fm], bg[fn], acc[fm][fn], 0, 0, 0);
        }
        __syncthreads();
    }

    const float scale = 0.044194173824159216f;   // 512^-0.5
    float bi[8], lw[8], lb[8];
    #pragma unroll
    for (int fn = 0; fn < 8; ++fn) {
        int colg = wcol + (fn << 4) + lane15;
        bi[fn] = bias[colg];
        lw[fn] = lnw[colg];
        lb[fn] = lnb[colg];
    }
    int r0 = (lane >> 4) << 2;
    #pragma unroll
    for (int fm = 0; fm < 2; ++fm) {
        #pragma unroll
        for (int j = 0; j < 4; ++j) {
            int r = (fm << 4) + r0 + j;
            const unsigned short* xrow = xb + (size_t)(i0 + r) * D;
            float s = 0.f, q = 0.f;
            #pragma unroll
            for (int fn = 0; fn < 8; ++fn) {
                int colg = wcol + (fn << 4) + lane15;
                float v = fmaxf(acc[fm][fn][j] + bi[fn], 0.f) * scale + bf2f(xrow[colg]);
                acc[fm][fn][j] = v;
                s += v;
                q += v * v;
            }
            #pragma unroll
            for (int m = 1; m < 16; m <<= 1) {
                s += __shfl_xor(s, m);
                q += __shfl_xor(q, m);
            }
            if (lane15 == 0) { psum[r][w] = s; psq[r][w] = q; }
        }
    }
    __syncthreads();
    #pragma unroll
    for (int fm = 0; fm < 2; ++fm) {
        #pragma unroll
        for (int j = 0; j < 4; ++j) {
            int r = (fm << 4) + r0 + j;
            float s = psum[r][0] + psum[r][1] + psum[r][2] + psum[r][3];
            float q = psq[r][0] + psq[r][1] + psq[r][2] + psq[r][3];
            float mu = s * (1.f / 512.f);
            float var = q * (1.f / 512.f) - mu * mu;
            float rstd = rsqrtf(var + LN_EPS);
            float* orow = out + (size_t)(i0 + r) * D;
            #pragma unroll
            for (int fn = 0; fn < 8; ++fn) {
                int colg = wcol + (fn << 4) + lane15;
                orow[colg] = lw[fn] * (acc[fm][fn][j] - mu) * rstd + lb[fn];
            }
        }
    }
}

extern "C" void kernel_launch(void* const* d_in, const int* in_sizes, int n_in,
                              void* d_out, int out_size, void* d_ws, size_t ws_size,
                              hipStream_t stream) {
    const float* x    = (const float*)d_in[0];
    const float* adj  = (const float*)d_in[1];
    const int*   pm   = (const int*)d_in[2];
    const float* W    = (const float*)d_in[3];
    const float* bias = (const float*)d_in[4];
    const float* lnw  = (const float*)d_in[5];
    const float* lnb  = (const float*)d_in[6];
    const float* ew   = (const float*)d_in[7];

    int BL = in_sizes[2];                 // B*L = 16384
    int L  = in_sizes[1] / BL;            // 2048
    int B  = BL / L;                      // 8
    int D  = in_sizes[0] / BL;            // 512

    char* ws = (char*)d_ws;
    size_t off = 0;
    float* dis   = (float*)(ws + off); off += (size_t)BL * 4;
    float* rs    = (float*)(ws + off); off += (size_t)BL * 4;
    float* rself = (float*)(ws + off); off += (size_t)BL * 4;
    unsigned short* pos = (unsigned short*)(ws + off); off += (size_t)BL * 2;
    unsigned short* idx = (unsigned short*)(ws + off); off += (size_t)BL * 2;
    int* cnt = (int*)(ws + off); off += 64;
    unsigned char* amc8 = (unsigned char*)(ws + off); off += (size_t)BL * L;
    unsigned char* yc8  = (unsigned char*)(ws + off); off += (size_t)BL * D;
    unsigned char* W8   = (unsigned char*)(ws + off); off += (size_t)D * D;
    unsigned char* agg8 = (unsigned char*)(ws + off); off += (size_t)BL * D;
    unsigned short* xb  = (unsigned short*)(ws + off); off += (size_t)BL * D * 2;

    float* out = (float*)d_out;
    int nx = (BL * D) / (256 * 8);        // 4096 xb data blocks
    int nw = (D * D) / (256 * 16);        // 64 W-convert blocks

    k_scan<<<B, 256, 0, stream>>>(pm, pos, idx, cnt, L);
    k_degxb<<<BL + nx + nw, 256, 0, stream>>>(adj, pm, ew, W, pos, cnt,
                                              dis, rs, rself, amc8, x, xb, agg8, W8, L, BL, nx);
    k_yt<<<dim3(L / 64, D / 64, B), 256, 0, stream>>>(xb, dis, idx, cnt, yc8, L, D);
    k_aggmm<<<B * (L / 64) * (D / 128), 256, 0, stream>>>(amc8, yc8, xb, rs, rself, idx, cnt, agg8, L, D);
    k_linln<<<BL / 32, 256, 0, stream>>>(agg8, W8, bias, xb, lnw, lnb, out);
}